// Round 13
// baseline (1659.314 us; speedup 1.0000x reference)
//
#include <hip/hip_runtime.h>

#define TPB 1024     // MLP kernel: 16 waves
#define BM 64
#define AS 128       // activation row stride in floats (swizzled)

// ===========================================================================
// CSR build: count -> block scan -> fixup -> scatter. Rebuilt every call.
// ===========================================================================
__global__ void count_kernel(const int* __restrict__ ei, int* __restrict__ cnt, int E)
{
    int e = blockIdx.x * blockDim.x + threadIdx.x;
    if (e >= E) return;
    atomicAdd(cnt + ei[E + e], 1);
}

__global__ void scan_blocks(const int* __restrict__ cnt, int* __restrict__ rs,
                            int* __restrict__ part, int N)
{
    __shared__ int sums[256];
    int t = threadIdx.x;
    int base = blockIdx.x * 2048 + t * 8;
    int v[8], s = 0;
#pragma unroll
    for (int i = 0; i < 8; i++) { int idx = base + i; v[i] = (idx < N) ? cnt[idx] : 0; s += v[i]; }
    sums[t] = s;
    __syncthreads();
    for (int off = 1; off < 256; off <<= 1) {
        int x = (t >= off) ? sums[t - off] : 0;
        __syncthreads();
        if (t >= off) sums[t] += x;
        __syncthreads();
    }
    int run = (t == 0) ? 0 : sums[t - 1];
#pragma unroll
    for (int i = 0; i < 8; i++) { int idx = base + i; if (idx < N) rs[idx] = run; run += v[i]; }
    if (t == 255) part[blockIdx.x] = sums[255];
}

__global__ void scan_part(int* __restrict__ part, int nb)
{
    __shared__ int sums[256];
    int t = threadIdx.x;
    int base = t * 8;
    int v[8], s = 0;
#pragma unroll
    for (int i = 0; i < 8; i++) { int idx = base + i; v[i] = (idx < nb) ? part[idx] : 0; s += v[i]; }
    sums[t] = s;
    __syncthreads();
    for (int off = 1; off < 256; off <<= 1) {
        int x = (t >= off) ? sums[t - off] : 0;
        __syncthreads();
        if (t >= off) sums[t] += x;
        __syncthreads();
    }
    int run = (t == 0) ? 0 : sums[t - 1];
#pragma unroll
    for (int i = 0; i < 8; i++) { int idx = base + i; if (idx < nb) part[idx] = run; run += v[i]; }
}

__global__ void scan_fixup(int* __restrict__ rs, int* __restrict__ cursor,
                           const int* __restrict__ part, int N, int E)
{
    int i = blockIdx.x * blockDim.x + threadIdx.x;
    if (i < N) { int v = rs[i] + part[i >> 11]; rs[i] = v; cursor[i] = v; }
    if (i == 0) rs[N] = E;
}

__global__ void scatter_kernel(const int* __restrict__ ei, int* __restrict__ cursor,
                               int* __restrict__ col, int E)
{
    int e = blockIdx.x * blockDim.x + threadIdx.x;
    if (e >= E) return;
    int d = ei[E + e];
    int p = atomicAdd(cursor + d, 1);
    col[p] = ei[e];
}

// ===========================================================================
// Standalone CSR gathers (separate kernels: their register pressure must not
// inflate the MLP kernel's budget — r9/r11 lesson). Latency-bound, no bounds.
// ===========================================================================
__global__ void gather_cla_kernel(const int* __restrict__ rs, const int* __restrict__ col,
                                  const float* __restrict__ state,
                                  float* __restrict__ agg, float* __restrict__ deg,
                                  int nvar2, int n)
{
    int gwave = (blockIdx.x * blockDim.x + threadIdx.x) >> 6;
    int lane = threadIdx.x & 63;
    for (int i = 0; i < 8; i++) {
        int node = gwave * 8 + i;
        if (node >= n) return;                 // node wave-uniform
        int d0 = rs[node], d1 = rs[node + 1];
        float acc = 0.0f;
        int e = d0;
        for (; e + 4 <= d1; e += 4) {
            int s0 = col[e], s1 = col[e + 1], s2 = col[e + 2], s3 = col[e + 3];
            float a0 = (s0 < nvar2) ? state[(long)s0 * 64 + lane] : 0.0f;
            float a1 = (s1 < nvar2) ? state[(long)s1 * 64 + lane] : 0.0f;
            float a2 = (s2 < nvar2) ? state[(long)s2 * 64 + lane] : 0.0f;
            float a3 = (s3 < nvar2) ? state[(long)s3 * 64 + lane] : 0.0f;
            acc += a0 + a1 + a2 + a3;
        }
        for (; e < d1; e++) {
            int s = col[e];
            if (s < nvar2) acc += state[(long)s * 64 + lane];
        }
        agg[(long)node * 64 + lane] = acc;
        if (lane == 0) deg[node] = (float)(d1 - d0);
    }
}

__global__ void gather_var_kernel(const int* __restrict__ rs, const int* __restrict__ col,
                                  const float* __restrict__ posr,
                                  float* __restrict__ agg, float* __restrict__ deg,
                                  int nvar, int n2)
{
    int gwave = (blockIdx.x * blockDim.x + threadIdx.x) >> 6;
    int lane = threadIdx.x & 63;
    int f = lane & 15, sub = lane >> 4;
    int nvar2 = 2 * nvar;
    for (int i = 0; i < 2; i++) {
        int node = gwave * 8 + i * 4 + sub;
        if (node < n2) {
            int d0 = rs[node], d1 = rs[node + 1];
            float acc = 0.0f;
            int e = d0;
            for (; e + 2 <= d1; e += 2) {
                int s0 = col[e], s1 = col[e + 1];
                float a0 = 0.0f, a1 = 0.0f;
                if (s0 < nvar2) {
                    a0 = posr[(long)((s0 < nvar) ? s0 : s0 - nvar) * 16 + f];
                    if (s0 >= nvar) a0 = -a0;
                }
                if (s1 < nvar2) {
                    a1 = posr[(long)((s1 < nvar) ? s1 : s1 - nvar) * 16 + f];
                    if (s1 >= nvar) a1 = -a1;
                }
                acc += a0 + a1;
            }
            for (; e < d1; e++) {
                int s = col[e];
                if (s < nvar2) {
                    float a = posr[(long)((s < nvar) ? s : s - nvar) * 16 + f];
                    acc += (s < nvar) ? a : -a;
                }
            }
            agg[(long)node * 16 + f] = acc;
            if (f == 0) deg[node] = (float)(d1 - d0);
        }
    }
}

// ===========================================================================
// act LDS swizzle: float4-slot XOR'd with (row&7).
// ===========================================================================
__device__ __forceinline__ int swz(int r, int col)
{
    return r * AS + ((((col >> 2) ^ (r & 7)) << 2) | (col & 3));
}

// ===========================================================================
// GEMM layer, 16 waves: wave = 64 rows (lane=row) x CW=C/16 columns.
// Weight loads are vector loads (hipcc does NOT scalarize pointer-chased
// uniform loads — r10's VGPR=56 at CW=16 proved it), so per-thread state is
// acc[CW<=8] + 1-2 wv float4 + act float4 ~= 24-28 VGPRs -> fits the 32-reg
// granule (8 waves/SIMD) with NO spill.
//   act[r][0:C] = f(sum_k act[r][k]*W[k][c] + scale(r)*bias[c])  in place
// ===========================================================================
template<int C, bool RELU>
__device__ __forceinline__ void scalar_gemm(
    float* __restrict__ act,
    const float* __restrict__ Wg, const float* __restrict__ bias_g,
    const float* __restrict__ ldeg,            // non-null: scale = ldeg[r]
    int K_real, int K_pad,                     // K_pad multiple of 4
    float* __restrict__ state_g, long base, int n)
{
    constexpr int CW = C / 16;                 // columns per wave (8 or 4)
    const int tid  = threadIdx.x;
    const int wid  = __builtin_amdgcn_readfirstlane(tid >> 6);  // uniform
    const int lane = tid & 63;
    const int r    = lane;                     // lane = row
    const int c0   = wid * CW;                 // wave-uniform column base

    float acc[CW];
#pragma unroll
    for (int j = 0; j < CW; j++) acc[j] = 0.0f;

    for (int k4 = 0; k4 < K_pad; k4 += 4) {
        float4 a = *(const float4*)(act + r * AS + (((k4 >> 2) ^ (r & 7)) << 2));
#pragma unroll
        for (int kk = 0; kk < 4; kk++) {
            int gk = k4 + kk;
            int wrow = (gk < K_real) ? gk : 0;       // clamp (act pad col = 0)
            float av = (&a.x)[kk];
            const float* wr = Wg + (long)wrow * C + c0;
#pragma unroll
            for (int j4 = 0; j4 < CW / 4; j4++) {
                float4 wv = *(const float4*)(wr + j4 * 4);
                acc[j4 * 4 + 0] = fmaf(av, wv.x, acc[j4 * 4 + 0]);
                acc[j4 * 4 + 1] = fmaf(av, wv.y, acc[j4 * 4 + 1]);
                acc[j4 * 4 + 2] = fmaf(av, wv.z, acc[j4 * 4 + 2]);
                acc[j4 * 4 + 3] = fmaf(av, wv.w, acc[j4 * 4 + 3]);
            }
        }
    }
    float scale = (ldeg != nullptr) ? ldeg[r] : 1.0f;
    __syncthreads();       // all waves' act reads complete
#pragma unroll
    for (int j4 = 0; j4 < CW / 4; j4++) {
        int cc = c0 + j4 * 4;
        float4 bv = *(const float4*)(bias_g + cc);
        float4 o;
        o.x = acc[j4 * 4 + 0] + scale * bv.x;
        o.y = acc[j4 * 4 + 1] + scale * bv.y;
        o.z = acc[j4 * 4 + 2] + scale * bv.z;
        o.w = acc[j4 * 4 + 3] + scale * bv.w;
        if (RELU) {
            o.x = fmaxf(o.x, 0.0f); o.y = fmaxf(o.y, 0.0f);
            o.z = fmaxf(o.z, 0.0f); o.w = fmaxf(o.w, 0.0f);
        }
        *(float4*)(act + r * AS + (((cc >> 2) ^ (r & 7)) << 2)) = o;
        if (state_g != nullptr && base + r < n)
            *(float4*)(state_g + (base + r) * 64 + cc) = o;
    }
    __syncthreads();       // new act visible
}

// ===========================================================================
// Pure-GEMM MLP kernel: stage agg -> LDS, layer0 -> update MLP -> predictor.
// TPB=1024 (16 waves), 32KB LDS -> 2 blocks/CU = 32 waves/CU = 8 waves/SIMD,
// needs VGPR <= 32 (pow2 granule). launch_bounds(1024,8) -> cap 32; CW<=8
// keeps true usage ~28 -> no spill (r11's spill was the fused gather).
// ===========================================================================
template<int K0>
__global__ __launch_bounds__(TPB, 8)
void mlp_kernel(const float* __restrict__ agg, const float* __restrict__ deg,
                const float* __restrict__ xg,
                const float* __restrict__ W0, const float* __restrict__ b0,
                const float* __restrict__ uW1, const float* __restrict__ ub1,
                const float* __restrict__ uW2, const float* __restrict__ ub2,
                const float* __restrict__ uW3, const float* __restrict__ ub3,
                const float* __restrict__ pW1, const float* __restrict__ pb1,
                const float* __restrict__ pW2, const float* __restrict__ pb2,
                const float* __restrict__ pW3, const float* __restrict__ pb3,
                float* __restrict__ state_g, float* __restrict__ outg, int n)
{
    __shared__ float act[BM * AS];
    __shared__ float ldeg[BM];

    const int tid = threadIdx.x;
    const long base = (long)blockIdx.x * BM;
    constexpr int KSH = (K0 == 64) ? 6 : 4;

    // ---- stage agg -> act[:, 0:K0] (coalesced read, swizzled write)
    for (int idx = tid; idx < BM * K0; idx += TPB) {
        int node = idx >> KSH, j = idx & (K0 - 1);
        float v = (base + node < n) ? agg[base * K0 + idx] : 0.0f;
        act[swz(node, j)] = v;
    }
    if (tid < BM) ldeg[tid] = (base + tid < n) ? deg[base + tid] : 0.0f;
    // ---- stage x into cols 64..66, zero col 67
    for (int idx = tid; idx < BM * 4; idx += TPB) {
        int node = idx >> 2, j = idx & 3;
        float v = 0.0f;
        if (j < 3 && base + node < n) v = xg[(base + node) * 3 + j];
        act[swz(node, 64 + j)] = v;
    }
    __syncthreads();

    // ---- layer0: msg = agg@W0 + deg*b0 (reads 0:K0, writes 0:64)
    scalar_gemm<64, false>(act, W0, b0, ldeg, K0, K0, nullptr, base, n);
    // ---- update MLP (uW1 is 67x128; K_pad=68 with wrow clamp, act[67]=0)
    scalar_gemm<128, true >(act, uW1, ub1, nullptr, 67, 68, nullptr, base, n);
    scalar_gemm<128, true >(act, uW2, ub2, nullptr, 128, 128, nullptr, base, n);
    scalar_gemm<64, false>(act, uW3, ub3, nullptr, 128, 128, state_g, base, n);
    // ---- predictor MLP
    scalar_gemm<128, true >(act, pW1, pb1, nullptr, 64, 64, nullptr, base, n);
    scalar_gemm<128, true >(act, pW2, pb2, nullptr, 128, 128, nullptr, base, n);

    // ---- predictor layer3: 128 -> 2 (tiny; pW3 hot in cache)
    if (tid < 128) {
        int r = tid >> 1, c = tid & 1;
        float acc = pb3[c];
        for (int k = 0; k < 128; k += 4) {
            float4 a = *(const float4*)(act + r * AS + (((k >> 2) ^ (r & 7)) << 2));
            acc = fmaf(a.x, pW3[(k + 0) * 2 + c], acc);
            acc = fmaf(a.y, pW3[(k + 1) * 2 + c], acc);
            acc = fmaf(a.z, pW3[(k + 2) * 2 + c], acc);
            acc = fmaf(a.w, pW3[(k + 3) * 2 + c], acc);
        }
        if (base + r < n) outg[(base + r) * 2 + c] = acc;
    }
}

// ===========================================================================
extern "C" void kernel_launch(void* const* d_in, const int* in_sizes, int n_in,
                              void* d_out, int out_size, void* d_ws, size_t ws_size,
                              hipStream_t stream)
{
    const float* x    = (const float*)d_in[0];
    const int*   ei   = (const int*)d_in[1];
    // d_in[2] = gate_type: fixed ordering [VAR*nvar, NEGVAR*nvar, CLAUSE*ncla]
    const float* posr = (const float*)d_in[3];
    const float* Wr   = (const float*)d_in[4];
    const float* br   = (const float*)d_in[5];
    const float* Wc   = (const float*)d_in[6];
    const float* bc   = (const float*)d_in[7];
    const float* uW1  = (const float*)d_in[8];
    const float* ub1  = (const float*)d_in[9];
    const float* uW2  = (const float*)d_in[10];
    const float* ub2  = (const float*)d_in[11];
    const float* uW3  = (const float*)d_in[12];
    const float* ub3  = (const float*)d_in[13];
    const float* pW1  = (const float*)d_in[14];
    const float* pb1  = (const float*)d_in[15];
    const float* pW2  = (const float*)d_in[16];
    const float* pb2  = (const float*)d_in[17];
    const float* pW3  = (const float*)d_in[18];
    const float* pb3  = (const float*)d_in[19];

    const int N     = in_sizes[0] / 3;
    const int E     = in_sizes[1] / 2;
    const int nvar  = in_sizes[3] / 16;
    const int nvar2 = 2 * nvar;
    const int ncla  = N - nvar2;

    // workspace carve-out
    int* cnt    = (int*)d_ws;              // [N]
    int* rs     = cnt + N;                 // [N+1]
    int* cursor = rs + N + 1;              // [N]
    int* part   = cursor + N;              // [2048]
    int* col    = part + 2048;             // [E]
    size_t foff = ((size_t)(col + E - (int*)d_ws) + 3) & ~(size_t)3;
    float* state = (float*)d_ws + foff;    // [2nvar*64]
    float* agg_v = state + (size_t)nvar2 * 64;   // [2nvar*16]
    float* deg_v = agg_v + (size_t)nvar2 * 16;   // [2nvar]
    float* agg_c = deg_v + nvar2;                // [ncla*64]
    float* deg_c = agg_c + (size_t)ncla * 64;    // [ncla]

    hipMemsetAsync(cnt, 0, (size_t)N * sizeof(int), stream);

    const int nb = (N + 2047) / 2048;
    count_kernel<<<(E + 255) / 256, 256, 0, stream>>>(ei, cnt, E);
    scan_blocks<<<nb, 256, 0, stream>>>(cnt, rs, part, N);
    scan_part<<<1, 256, 0, stream>>>(part, nb);
    scan_fixup<<<(N + 255) / 256, 256, 0, stream>>>(rs, cursor, part, N, E);
    scatter_kernel<<<(E + 255) / 256, 256, 0, stream>>>(ei, cursor, col, E);

    {   // var/negvar gather (CSR -> agg_v, deg_v)
        int blocks = (nvar2 + 31) / 32;    // 4 waves x 8 nodes per block
        gather_var_kernel<<<blocks, 256, 0, stream>>>(rs, col, posr,
                                                      agg_v, deg_v, nvar, nvar2);
    }
    {   // var/negvar MLP (writes state + out)
        int blocks = (nvar2 + BM - 1) / BM;
        mlp_kernel<16><<<blocks, TPB, 0, stream>>>(
            agg_v, deg_v, x, Wr, br,
            uW1, ub1, uW2, ub2, uW3, ub3,
            pW1, pb1, pW2, pb2, pW3, pb3,
            state, (float*)d_out, nvar2);
    }
    {   // clause gather (CSR rows offset by 2nvar -> agg_c, deg_c)
        int blocks = (ncla + 31) / 32;
        gather_cla_kernel<<<blocks, 256, 0, stream>>>(rs + nvar2, col, state,
                                                      agg_c, deg_c, nvar2, ncla);
    }
    {   // clause MLP
        int blocks = (ncla + BM - 1) / BM;
        mlp_kernel<64><<<blocks, TPB, 0, stream>>>(
            agg_c, deg_c, x + (size_t)nvar2 * 3, Wc, bc,
            uW1, ub1, uW2, ub2, uW3, ub3,
            pW1, pb1, pW2, pb2, pW3, pb3,
            nullptr, (float*)d_out + (size_t)nvar2 * 2, ncla);
    }
}

// Round 14
// 1291.092 us; speedup vs baseline: 1.2852x; 1.2852x over previous
//
#include <hip/hip_runtime.h>

#define TPB 512
#define BM 64

typedef float f32x4 __attribute__((ext_vector_type(4)));
typedef short s16x8 __attribute__((ext_vector_type(8)));

// ===========================================================================
// bf16 split helpers (round-to-nearest-even-ish)
// ===========================================================================
__device__ __forceinline__ unsigned short f2bh(float f)
{
    unsigned u = __float_as_uint(f);
    unsigned r = u + 0x7fffu + ((u >> 16) & 1u);
    return (unsigned short)(r >> 16);
}
__device__ __forceinline__ float bh2f(unsigned short h)
{
    return __uint_as_float((unsigned)h << 16);
}

// act LDS swizzle (ushort units): 16B slot index XOR'd with row&7
__device__ __forceinline__ int aswz(int r, int k)
{
    return r * 128 + ((((k >> 3) ^ (r & 7)) << 3) | (k & 7));
}

// ===========================================================================
// CSR build: count -> block scan -> fixup -> scatter. Rebuilt every call.
// ===========================================================================
__global__ void count_kernel(const int* __restrict__ ei, int* __restrict__ cnt, int E)
{
    int e = blockIdx.x * blockDim.x + threadIdx.x;
    if (e >= E) return;
    atomicAdd(cnt + ei[E + e], 1);
}

__global__ void scan_blocks(const int* __restrict__ cnt, int* __restrict__ rs,
                            int* __restrict__ part, int N)
{
    __shared__ int sums[256];
    int t = threadIdx.x;
    int base = blockIdx.x * 2048 + t * 8;
    int v[8], s = 0;
#pragma unroll
    for (int i = 0; i < 8; i++) { int idx = base + i; v[i] = (idx < N) ? cnt[idx] : 0; s += v[i]; }
    sums[t] = s;
    __syncthreads();
    for (int off = 1; off < 256; off <<= 1) {
        int x = (t >= off) ? sums[t - off] : 0;
        __syncthreads();
        if (t >= off) sums[t] += x;
        __syncthreads();
    }
    int run = (t == 0) ? 0 : sums[t - 1];
#pragma unroll
    for (int i = 0; i < 8; i++) { int idx = base + i; if (idx < N) rs[idx] = run; run += v[i]; }
    if (t == 255) part[blockIdx.x] = sums[255];
}

__global__ void scan_part(int* __restrict__ part, int nb)
{
    __shared__ int sums[256];
    int t = threadIdx.x;
    int base = t * 8;
    int v[8], s = 0;
#pragma unroll
    for (int i = 0; i < 8; i++) { int idx = base + i; v[i] = (idx < nb) ? part[idx] : 0; s += v[i]; }
    sums[t] = s;
    __syncthreads();
    for (int off = 1; off < 256; off <<= 1) {
        int x = (t >= off) ? sums[t - off] : 0;
        __syncthreads();
        if (t >= off) sums[t] += x;
        __syncthreads();
    }
    int run = (t == 0) ? 0 : sums[t - 1];
#pragma unroll
    for (int i = 0; i < 8; i++) { int idx = base + i; if (idx < nb) part[idx] = run; run += v[i]; }
}

__global__ void scan_fixup(int* __restrict__ rs, int* __restrict__ cursor,
                           const int* __restrict__ part, int N, int E)
{
    int i = blockIdx.x * blockDim.x + threadIdx.x;
    if (i < N) { int v = rs[i] + part[i >> 11]; rs[i] = v; cursor[i] = v; }
    if (i == 0) rs[N] = E;
}

__global__ void scatter_kernel(const int* __restrict__ ei, int* __restrict__ cursor,
                               int* __restrict__ col, int E)
{
    int e = blockIdx.x * blockDim.x + threadIdx.x;
    if (e >= E) return;
    int d = ei[E + e];
    int p = atomicAdd(cursor + d, 1);
    col[p] = ei[e];
}

// ===========================================================================
// Standalone CSR gathers (separate kernels so their register pressure never
// touches the MLP kernel — r9/r11 lesson). Latency-bound, no launch bounds.
// ===========================================================================
__global__ void gather_cla_kernel(const int* __restrict__ rs, const int* __restrict__ col,
                                  const float* __restrict__ state,
                                  float* __restrict__ agg, float* __restrict__ deg,
                                  int nvar2, int n)
{
    int gwave = (blockIdx.x * blockDim.x + threadIdx.x) >> 6;
    int lane = threadIdx.x & 63;
    for (int i = 0; i < 8; i++) {
        int node = gwave * 8 + i;
        if (node >= n) return;
        int d0 = rs[node], d1 = rs[node + 1];
        float acc = 0.0f;
        int e = d0;
        for (; e + 4 <= d1; e += 4) {
            int s0 = col[e], s1 = col[e + 1], s2 = col[e + 2], s3 = col[e + 3];
            float a0 = (s0 < nvar2) ? state[(long)s0 * 64 + lane] : 0.0f;
            float a1 = (s1 < nvar2) ? state[(long)s1 * 64 + lane] : 0.0f;
            float a2 = (s2 < nvar2) ? state[(long)s2 * 64 + lane] : 0.0f;
            float a3 = (s3 < nvar2) ? state[(long)s3 * 64 + lane] : 0.0f;
            acc += a0 + a1 + a2 + a3;
        }
        for (; e < d1; e++) {
            int s = col[e];
            if (s < nvar2) acc += state[(long)s * 64 + lane];
        }
        agg[(long)node * 64 + lane] = acc;
        if (lane == 0) deg[node] = (float)(d1 - d0);
    }
}

__global__ void gather_var_kernel(const int* __restrict__ rs, const int* __restrict__ col,
                                  const float* __restrict__ posr,
                                  float* __restrict__ agg, float* __restrict__ deg,
                                  int nvar, int n2)
{
    int gwave = (blockIdx.x * blockDim.x + threadIdx.x) >> 6;
    int lane = threadIdx.x & 63;
    int f = lane & 15, sub = lane >> 4;
    int nvar2 = 2 * nvar;
    for (int i = 0; i < 2; i++) {
        int node = gwave * 8 + i * 4 + sub;
        if (node < n2) {
            int d0 = rs[node], d1 = rs[node + 1];
            float acc = 0.0f;
            int e = d0;
            for (; e + 2 <= d1; e += 2) {
                int s0 = col[e], s1 = col[e + 1];
                float a0 = 0.0f, a1 = 0.0f;
                if (s0 < nvar2) {
                    a0 = posr[(long)((s0 < nvar) ? s0 : s0 - nvar) * 16 + f];
                    if (s0 >= nvar) a0 = -a0;
                }
                if (s1 < nvar2) {
                    a1 = posr[(long)((s1 < nvar) ? s1 : s1 - nvar) * 16 + f];
                    if (s1 >= nvar) a1 = -a1;
                }
                acc += a0 + a1;
            }
            for (; e < d1; e++) {
                int s = col[e];
                if (s < nvar2) {
                    float a = posr[(long)((s < nvar) ? s : s - nvar) * 16 + f];
                    acc += (s < nvar) ? a : -a;
                }
            }
            agg[(long)node * 16 + f] = acc;
            if (f == 0) deg[node] = (float)(d1 - d0);
        }
    }
}

// ===========================================================================
// Weight prep: fp32 W[K][C] -> fragment-ordered bf16 hi/lo for
// mfma_f32_16x16x32_bf16 B-operand. Lane l of fragment (col-tile ct, k-step
// ks) needs col = ct*16 + (l&15), k = ks*32 + 4*(l>>4) + (i&3) + 16*(i>>2).
// Stored so each lane's 8 bf16 are one contiguous 16B load:
//   dst[((ct*NKS + ks)*64 + l)*8 + i]
// ===========================================================================
__global__ void prep_w(const float* __restrict__ W, int K_real, int C, int NKS,
                       unsigned short* __restrict__ dhi, unsigned short* __restrict__ dlo)
{
    int t = blockIdx.x * blockDim.x + threadIdx.x;
    int total = (C / 16) * NKS * 64;
    if (t >= total) return;
    int l = t & 63;
    int rest = t >> 6;
    int ks = rest % NKS;
    int ct = rest / NKS;
    int colg = ct * 16 + (l & 15);
#pragma unroll
    for (int i = 0; i < 8; i++) {
        int k = ks * 32 + 4 * (l >> 4) + (i & 3) + 16 * (i >> 2);
        float v = (k < K_real) ? W[(long)k * C + colg] : 0.0f;
        unsigned short h = f2bh(v);
        dhi[(long)t * 8 + i] = h;
        dlo[(long)t * 8 + i] = f2bh(v - bh2f(h));
    }
}

// ===========================================================================
// Split-bf16 MFMA GEMM layer (in-place on LDS act hi/lo):
//   act[r][0:C] = f( act[r][0:K] @ W + scale(r)*bias )
// 8 waves: rows (w&3)*16, col-half (w>>2). NT tiles/wave (C/32), NKS k-steps.
// Per (ks, tile): 3 MFMA (hi*hi + hi*lo + lo*hi) -> fp32-grade accuracy.
// A-frag: row = r0+(l&15), k = ks*32 + 4*(l>>4) + {0..3, 16..19}.
// C/D: col = tile*16 + (l&15), row = r0 + (l>>4)*4 + i  [m89 verified].
// ===========================================================================
template<int NKS, int NT, bool RELU, bool L0S>
__device__ __forceinline__ void mfma_gemm(
    unsigned short* __restrict__ ah, unsigned short* __restrict__ al,
    const unsigned short* __restrict__ wh, const unsigned short* __restrict__ wl,
    const float* __restrict__ bias, const float* __restrict__ ldeg,
    float* __restrict__ state_g, long base, int n)
{
    const int tid = threadIdx.x;
    const int w = tid >> 6, l = tid & 63;
    const int r0 = (w & 3) * 16;
    const int half = w >> 2;
    const int ar = r0 + (l & 15);
    const int ag = (l >> 4) * 4;

    f32x4 acc[NT];
#pragma unroll
    for (int t = 0; t < NT; t++) { f32x4 z = {0.f, 0.f, 0.f, 0.f}; acc[t] = z; }

#pragma unroll
    for (int ks = 0; ks < NKS; ks++) {
        int k0 = ks * 32 + ag;
        uint2 h0 = *(const uint2*)(ah + aswz(ar, k0));
        uint2 h1 = *(const uint2*)(ah + aswz(ar, k0 + 16));
        uint2 g0 = *(const uint2*)(al + aswz(ar, k0));
        uint2 g1 = *(const uint2*)(al + aswz(ar, k0 + 16));
        union { uint4 u; s16x8 s; } fah, fal;
        fah.u = make_uint4(h0.x, h0.y, h1.x, h1.y);
        fal.u = make_uint4(g0.x, g0.y, g1.x, g1.y);
#pragma unroll
        for (int t = 0; t < NT; t++) {
            int ct = half * NT + t;
            long off = (long)((ct * NKS + ks) * 64 + l) * 8;
            union { uint4 u; s16x8 s; } fbh, fbl;
            fbh.u = *(const uint4*)(wh + off);
            fbl.u = *(const uint4*)(wl + off);
            acc[t] = __builtin_amdgcn_mfma_f32_16x16x32_bf16(fah.s, fbh.s, acc[t], 0, 0, 0);
            acc[t] = __builtin_amdgcn_mfma_f32_16x16x32_bf16(fah.s, fbl.s, acc[t], 0, 0, 0);
            acc[t] = __builtin_amdgcn_mfma_f32_16x16x32_bf16(fal.s, fbh.s, acc[t], 0, 0, 0);
        }
    }
    __syncthreads();   // all waves done reading act
    const int orow = r0 + (l >> 4) * 4;
#pragma unroll
    for (int t = 0; t < NT; t++) {
        int colg = (half * NT + t) * 16 + (l & 15);
        float bv = bias[colg];
#pragma unroll
        for (int i = 0; i < 4; i++) {
            int row = orow + i;
            float sc = L0S ? ldeg[row] : 1.0f;
            float o = acc[t][i] + sc * bv;
            if (RELU) o = fmaxf(o, 0.0f);
            unsigned short h = f2bh(o);
            ah[aswz(row, colg)] = h;
            al[aswz(row, colg)] = f2bh(o - bh2f(h));
            if (state_g != nullptr && base + row < n)
                state_g[(base + row) * 64 + colg] = o;
        }
    }
    __syncthreads();   // new act visible
}

// ===========================================================================
// MLP kernel: stage agg/x -> bf16 hi/lo LDS act, then 6 MFMA layers + pW3.
// LDS = 2 x 16KB act + ldeg.
// ===========================================================================
template<int K0>
__global__ __launch_bounds__(TPB)
void mlp_kernel(const float* __restrict__ agg, const float* __restrict__ deg,
                const float* __restrict__ xg,
                const unsigned short* w0h, const unsigned short* w0l,
                const unsigned short* u1h, const unsigned short* u1l,
                const unsigned short* u2h, const unsigned short* u2l,
                const unsigned short* u3h, const unsigned short* u3l,
                const unsigned short* p1h, const unsigned short* p1l,
                const unsigned short* p2h, const unsigned short* p2l,
                const float* __restrict__ b0, const float* __restrict__ ub1,
                const float* __restrict__ ub2, const float* __restrict__ ub3,
                const float* __restrict__ pb1, const float* __restrict__ pb2,
                const float* __restrict__ pW3, const float* __restrict__ pb3,
                float* __restrict__ state_g, float* __restrict__ outg, int n)
{
    __shared__ unsigned short ah[64 * 128];
    __shared__ unsigned short al[64 * 128];
    __shared__ float ldeg[BM];

    const int tid = threadIdx.x;
    const long base = (long)blockIdx.x * BM;

    // ---- stage: cols [0,K0) = agg, [64,67) = x, rest of [0,96) = 0
    for (int idx = tid; idx < BM * 96; idx += TPB) {
        int node = idx / 96, c = idx - node * 96;
        float v = 0.0f;
        if (base + node < n) {
            if (c < K0)                 v = agg[(base + node) * K0 + c];
            else if (c >= 64 && c < 67) v = xg[(base + node) * 3 + (c - 64)];
        }
        unsigned short h = f2bh(v);
        ah[aswz(node, c)] = h;
        al[aswz(node, c)] = f2bh(v - bh2f(h));
    }
    if (tid < BM) ldeg[tid] = (base + tid < n) ? deg[base + tid] : 0.0f;
    __syncthreads();

    constexpr int NKS0 = (K0 == 64) ? 2 : 1;
    // layer0: K0 -> 64, bias scaled by deg
    mfma_gemm<NKS0, 2, false, true >(ah, al, w0h, w0l, b0, ldeg, nullptr, base, n);
    // update MLP: 96(67) -> 128 relu, 128 -> 128 relu, 128 -> 64 (state out)
    mfma_gemm<3, 4, true,  false>(ah, al, u1h, u1l, ub1, ldeg, nullptr, base, n);
    mfma_gemm<4, 4, true,  false>(ah, al, u2h, u2l, ub2, ldeg, nullptr, base, n);
    mfma_gemm<4, 2, false, false>(ah, al, u3h, u3l, ub3, ldeg, state_g, base, n);
    // predictor: 64 -> 128 relu, 128 -> 128 relu
    mfma_gemm<2, 4, true,  false>(ah, al, p1h, p1l, pb1, ldeg, nullptr, base, n);
    mfma_gemm<4, 4, true,  false>(ah, al, p2h, p2l, pb2, ldeg, nullptr, base, n);

    // ---- pW3: 128 -> 2 on VALU (reconstruct fp32 act = hi + lo)
    if (tid < 128) {
        int r = tid >> 1, c = tid & 1;
        float acc = pb3[c];
        for (int k = 0; k < 128; k++) {
            float f = bh2f(ah[aswz(r, k)]) + bh2f(al[aswz(r, k)]);
            acc = fmaf(f, pW3[k * 2 + c], acc);
        }
        if (base + r < n) outg[(base + r) * 2 + c] = acc;
    }
}

// ===========================================================================
extern "C" void kernel_launch(void* const* d_in, const int* in_sizes, int n_in,
                              void* d_out, int out_size, void* d_ws, size_t ws_size,
                              hipStream_t stream)
{
    const float* x    = (const float*)d_in[0];
    const int*   ei   = (const int*)d_in[1];
    // d_in[2] = gate_type: fixed ordering [VAR*nvar, NEGVAR*nvar, CLAUSE*ncla]
    const float* posr = (const float*)d_in[3];
    const float* Wr   = (const float*)d_in[4];
    const float* br   = (const float*)d_in[5];
    const float* Wc   = (const float*)d_in[6];
    const float* bc   = (const float*)d_in[7];
    const float* uW1  = (const float*)d_in[8];
    const float* ub1  = (const float*)d_in[9];
    const float* uW2  = (const float*)d_in[10];
    const float* ub2  = (const float*)d_in[11];
    const float* uW3  = (const float*)d_in[12];
    const float* ub3  = (const float*)d_in[13];
    const float* pW1  = (const float*)d_in[14];
    const float* pb1  = (const float*)d_in[15];
    const float* pW2  = (const float*)d_in[16];
    const float* pb2  = (const float*)d_in[17];
    const float* pW3  = (const float*)d_in[18];
    const float* pb3  = (const float*)d_in[19];

    const int N     = in_sizes[0] / 3;
    const int E     = in_sizes[1] / 2;
    const int nvar  = in_sizes[3] / 16;
    const int nvar2 = 2 * nvar;
    const int ncla  = N - nvar2;

    // workspace carve-out
    int* cnt    = (int*)d_ws;              // [N]
    int* rs     = cnt + N;                 // [N+1]
    int* cursor = rs + N + 1;              // [N]
    int* part   = cursor + N;              // [2048]
    int* col    = part + 2048;             // [E]
    size_t foff = ((size_t)(col + E - (int*)d_ws) + 3) & ~(size_t)3;
    float* state = (float*)d_ws + foff;    // [2nvar*64]
    float* agg_v = state + (size_t)nvar2 * 64;   // [2nvar*16]
    float* deg_v = agg_v + (size_t)nvar2 * 16;   // [2nvar]
    float* agg_c = deg_v + nvar2;                // [ncla*64]
    float* deg_c = agg_c + (size_t)ncla * 64;    // [ncla]
    uintptr_t wp = ((uintptr_t)(deg_c + ncla) + 15) & ~(uintptr_t)15;
    unsigned short* H = (unsigned short*)wp;     // fragment-ordered bf16 hi
    const int TH = 67584;                        // total ushorts of all layers
    unsigned short* L = H + TH;                  // bf16 lo
    // per-layer offsets (C*Kpad ushorts each)
    const int oW0v = 0, oW0c = 2048, oU1 = 6144, oU2 = 18432,
              oU3 = 34816, oP1 = 43008, oP2 = 51200;

    // ---- weight prep (tiny, once per call)
    prep_w<<<1, 256, 0, stream>>>(Wr, 16, 64, 1, H + oW0v, L + oW0v);
    prep_w<<<2, 256, 0, stream>>>(Wc, 64, 64, 2, H + oW0c, L + oW0c);
    prep_w<<<6, 256, 0, stream>>>(uW1, 67, 128, 3, H + oU1, L + oU1);
    prep_w<<<8, 256, 0, stream>>>(uW2, 128, 128, 4, H + oU2, L + oU2);
    prep_w<<<4, 256, 0, stream>>>(uW3, 128, 64, 4, H + oU3, L + oU3);
    prep_w<<<4, 256, 0, stream>>>(pW1, 64, 128, 2, H + oP1, L + oP1);
    prep_w<<<8, 256, 0, stream>>>(pW2, 128, 128, 4, H + oP2, L + oP2);

    hipMemsetAsync(cnt, 0, (size_t)N * sizeof(int), stream);

    const int nb = (N + 2047) / 2048;
    count_kernel<<<(E + 255) / 256, 256, 0, stream>>>(ei, cnt, E);
    scan_blocks<<<nb, 256, 0, stream>>>(cnt, rs, part, N);
    scan_part<<<1, 256, 0, stream>>>(part, nb);
    scan_fixup<<<(N + 255) / 256, 256, 0, stream>>>(rs, cursor, part, N, E);
    scatter_kernel<<<(E + 255) / 256, 256, 0, stream>>>(ei, cursor, col, E);

    {   // var/negvar gather (CSR -> agg_v, deg_v)
        int blocks = (nvar2 + 31) / 32;
        gather_var_kernel<<<blocks, 256, 0, stream>>>(rs, col, posr,
                                                      agg_v, deg_v, nvar, nvar2);
    }
    {   // var/negvar MLP (writes state + out)
        int blocks = (nvar2 + BM - 1) / BM;
        mlp_kernel<16><<<blocks, TPB, 0, stream>>>(
            agg_v, deg_v, x,
            H + oW0v, L + oW0v, H + oU1, L + oU1, H + oU2, L + oU2,
            H + oU3, L + oU3, H + oP1, L + oP1, H + oP2, L + oP2,
            br, ub1, ub2, ub3, pb1, pb2, pW3, pb3,
            state, (float*)d_out, nvar2);
    }
    {   // clause gather (CSR rows offset by 2nvar -> agg_c, deg_c)
        int blocks = (ncla + 31) / 32;
        gather_cla_kernel<<<blocks, 256, 0, stream>>>(rs + nvar2, col, state,
                                                      agg_c, deg_c, nvar2, ncla);
    }
    {   // clause MLP
        int blocks = (ncla + BM - 1) / BM;
        mlp_kernel<64><<<blocks, TPB, 0, stream>>>(
            agg_c, deg_c, x + (size_t)nvar2 * 3,
            H + oW0c, L + oW0c, H + oU1, L + oU1, H + oU2, L + oU2,
            H + oU3, L + oU3, H + oP1, L + oP1, H + oP2, L + oP2,
            bc, ub1, ub2, ub3, pb1, pb2, pW3, pb3,
            nullptr, (float*)d_out + (size_t)nvar2 * 2, ncla);
    }
}

// Round 15
// 1182.419 us; speedup vs baseline: 1.4033x; 1.0919x over previous
//
#include <hip/hip_runtime.h>

#define MTPB 1024    // MLP kernel: 16 waves
#define BM 64

typedef float f32x4 __attribute__((ext_vector_type(4)));
typedef short s16x8 __attribute__((ext_vector_type(8)));

// ===========================================================================
// bf16 split helpers
// ===========================================================================
__device__ __forceinline__ unsigned short f2bh(float f)
{
    unsigned u = __float_as_uint(f);
    unsigned r = u + 0x7fffu + ((u >> 16) & 1u);
    return (unsigned short)(r >> 16);
}
__device__ __forceinline__ float bh2f(unsigned short h)
{
    return __uint_as_float((unsigned)h << 16);
}

// act LDS swizzle (ushort units): 16B slot index XOR'd with row&7
__device__ __forceinline__ int aswz(int r, int k)
{
    return r * 128 + ((((k >> 3) ^ (r & 7)) << 3) | (k & 7));
}

// ===========================================================================
// CSR build: count -> block scan -> fixup -> scatter. Rebuilt every call.
// ===========================================================================
__global__ void count_kernel(const int* __restrict__ ei, int* __restrict__ cnt, int E)
{
    int e = blockIdx.x * blockDim.x + threadIdx.x;
    if (e >= E) return;
    atomicAdd(cnt + ei[E + e], 1);
}

__global__ void scan_blocks(const int* __restrict__ cnt, int* __restrict__ rs,
                            int* __restrict__ part, int N)
{
    __shared__ int sums[256];
    int t = threadIdx.x;
    int base = blockIdx.x * 2048 + t * 8;
    int v[8], s = 0;
#pragma unroll
    for (int i = 0; i < 8; i++) { int idx = base + i; v[i] = (idx < N) ? cnt[idx] : 0; s += v[i]; }
    sums[t] = s;
    __syncthreads();
    for (int off = 1; off < 256; off <<= 1) {
        int x = (t >= off) ? sums[t - off] : 0;
        __syncthreads();
        if (t >= off) sums[t] += x;
        __syncthreads();
    }
    int run = (t == 0) ? 0 : sums[t - 1];
#pragma unroll
    for (int i = 0; i < 8; i++) { int idx = base + i; if (idx < N) rs[idx] = run; run += v[i]; }
    if (t == 255) part[blockIdx.x] = sums[255];
}

__global__ void scan_part(int* __restrict__ part, int nb)
{
    __shared__ int sums[256];
    int t = threadIdx.x;
    int base = t * 8;
    int v[8], s = 0;
#pragma unroll
    for (int i = 0; i < 8; i++) { int idx = base + i; v[i] = (idx < nb) ? part[idx] : 0; s += v[i]; }
    sums[t] = s;
    __syncthreads();
    for (int off = 1; off < 256; off <<= 1) {
        int x = (t >= off) ? sums[t - off] : 0;
        __syncthreads();
        if (t >= off) sums[t] += x;
        __syncthreads();
    }
    int run = (t == 0) ? 0 : sums[t - 1];
#pragma unroll
    for (int i = 0; i < 8; i++) { int idx = base + i; if (idx < nb) part[idx] = run; run += v[i]; }
}

__global__ void scan_fixup(int* __restrict__ rs, int* __restrict__ cursor,
                           const int* __restrict__ part, int N, int E)
{
    int i = blockIdx.x * blockDim.x + threadIdx.x;
    if (i < N) { int v = rs[i] + part[i >> 11]; rs[i] = v; cursor[i] = v; }
    if (i == 0) rs[N] = E;
}

__global__ void scatter_kernel(const int* __restrict__ ei, int* __restrict__ cursor,
                               int* __restrict__ col, int E)
{
    int e = blockIdx.x * blockDim.x + threadIdx.x;
    if (e >= E) return;
    int d = ei[E + e];
    int p = atomicAdd(cursor + d, 1);
    col[p] = ei[e];
}

// ===========================================================================
// Standalone CSR gathers (separate kernels so their register pressure never
// touches the MLP kernel — r9/r11 lesson). Latency-bound, no launch bounds.
// ===========================================================================
__global__ void gather_cla_kernel(const int* __restrict__ rs, const int* __restrict__ col,
                                  const float* __restrict__ state,
                                  float* __restrict__ agg, float* __restrict__ deg,
                                  int nvar2, int n)
{
    int gwave = (blockIdx.x * blockDim.x + threadIdx.x) >> 6;
    int lane = threadIdx.x & 63;
    for (int i = 0; i < 8; i++) {
        int node = gwave * 8 + i;
        if (node >= n) return;
        int d0 = rs[node], d1 = rs[node + 1];
        float acc = 0.0f;
        int e = d0;
        for (; e + 4 <= d1; e += 4) {
            int s0 = col[e], s1 = col[e + 1], s2 = col[e + 2], s3 = col[e + 3];
            float a0 = (s0 < nvar2) ? state[(long)s0 * 64 + lane] : 0.0f;
            float a1 = (s1 < nvar2) ? state[(long)s1 * 64 + lane] : 0.0f;
            float a2 = (s2 < nvar2) ? state[(long)s2 * 64 + lane] : 0.0f;
            float a3 = (s3 < nvar2) ? state[(long)s3 * 64 + lane] : 0.0f;
            acc += a0 + a1 + a2 + a3;
        }
        for (; e < d1; e++) {
            int s = col[e];
            if (s < nvar2) acc += state[(long)s * 64 + lane];
        }
        agg[(long)node * 64 + lane] = acc;
        if (lane == 0) deg[node] = (float)(d1 - d0);
    }
}

__global__ void gather_var_kernel(const int* __restrict__ rs, const int* __restrict__ col,
                                  const float* __restrict__ posr,
                                  float* __restrict__ agg, float* __restrict__ deg,
                                  int nvar, int n2)
{
    int gwave = (blockIdx.x * blockDim.x + threadIdx.x) >> 6;
    int lane = threadIdx.x & 63;
    int f = lane & 15, sub = lane >> 4;
    int nvar2 = 2 * nvar;
    for (int i = 0; i < 2; i++) {
        int node = gwave * 8 + i * 4 + sub;
        if (node < n2) {
            int d0 = rs[node], d1 = rs[node + 1];
            float acc = 0.0f;
            int e = d0;
            for (; e + 2 <= d1; e += 2) {
                int s0 = col[e], s1 = col[e + 1];
                float a0 = 0.0f, a1 = 0.0f;
                if (s0 < nvar2) {
                    a0 = posr[(long)((s0 < nvar) ? s0 : s0 - nvar) * 16 + f];
                    if (s0 >= nvar) a0 = -a0;
                }
                if (s1 < nvar2) {
                    a1 = posr[(long)((s1 < nvar) ? s1 : s1 - nvar) * 16 + f];
                    if (s1 >= nvar) a1 = -a1;
                }
                acc += a0 + a1;
            }
            for (; e < d1; e++) {
                int s = col[e];
                if (s < nvar2) {
                    float a = posr[(long)((s < nvar) ? s : s - nvar) * 16 + f];
                    acc += (s < nvar) ? a : -a;
                }
            }
            agg[(long)node * 16 + f] = acc;
            if (f == 0) deg[node] = (float)(d1 - d0);
        }
    }
}

// ===========================================================================
// Weight prep: fp32 W[K][C] -> fragment-ordered bf16 hi/lo for
// mfma_f32_16x16x32_bf16 B-operand. Lane l of fragment (col-tile ct, k-step
// ks): col = ct*16 + (l&15), k = ks*32 + 4*(l>>4) + (i&3) + 16*(i>>2).
// Stored so each lane's 8 bf16 are one contiguous 16B load.
// ===========================================================================
__global__ void prep_w(const float* __restrict__ W, int K_real, int C, int NKS,
                       unsigned short* __restrict__ dhi, unsigned short* __restrict__ dlo)
{
    int t = blockIdx.x * blockDim.x + threadIdx.x;
    int total = (C / 16) * NKS * 64;
    if (t >= total) return;
    int l = t & 63;
    int rest = t >> 6;
    int ks = rest % NKS;
    int ct = rest / NKS;
    int colg = ct * 16 + (l & 15);
#pragma unroll
    for (int i = 0; i < 8; i++) {
        int k = ks * 32 + 4 * (l >> 4) + (i & 3) + 16 * (i >> 2);
        float v = (k < K_real) ? W[(long)k * C + colg] : 0.0f;
        unsigned short h = f2bh(v);
        dhi[(long)t * 8 + i] = h;
        dlo[(long)t * 8 + i] = f2bh(v - bh2f(h));
    }
}

// ===========================================================================
// Split-bf16 MFMA GEMM layer, PING-PONG buffers (in != out), 16 waves:
// wave = (row-stripe w&3) x (col-quarter w>>2); NT tiles/wave (C = NT*64).
// 3 MFMA per (ks,tile): hi*hi + hi*lo + lo*hi = fp32-grade accuracy.
// ONE barrier per layer (epilogue writes a different buffer than reads).
// ===========================================================================
template<int NKS, int NT, bool RELU, bool L0S>
__device__ __forceinline__ void mfma_gemm(
    const unsigned short* __restrict__ ih, const unsigned short* __restrict__ il,
    unsigned short* __restrict__ oh, unsigned short* __restrict__ ol,
    const unsigned short* __restrict__ wh, const unsigned short* __restrict__ wl,
    const float* __restrict__ bias, const float* __restrict__ ldeg,
    float* __restrict__ state_g, long base, int n)
{
    const int tid = threadIdx.x;
    const int w = tid >> 6, l = tid & 63;
    const int rs_ = w & 3;            // row stripe (16 rows)
    const int cq = w >> 2;            // col quarter
    const int ar = rs_ * 16 + (l & 15);
    const int ag = (l >> 4) * 4;

    f32x4 acc[NT];
#pragma unroll
    for (int t = 0; t < NT; t++) { f32x4 z = {0.f, 0.f, 0.f, 0.f}; acc[t] = z; }

#pragma unroll
    for (int ks = 0; ks < NKS; ks++) {
        int k0 = ks * 32 + ag;
        uint2 h0 = *(const uint2*)(ih + aswz(ar, k0));
        uint2 h1 = *(const uint2*)(ih + aswz(ar, k0 + 16));
        uint2 g0 = *(const uint2*)(il + aswz(ar, k0));
        uint2 g1 = *(const uint2*)(il + aswz(ar, k0 + 16));
        union { uint4 u; s16x8 s; } fah, fal;
        fah.u = make_uint4(h0.x, h0.y, h1.x, h1.y);
        fal.u = make_uint4(g0.x, g0.y, g1.x, g1.y);
#pragma unroll
        for (int t = 0; t < NT; t++) {
            int ct = cq * NT + t;
            long off = (long)((ct * NKS + ks) * 64 + l) * 8;
            union { uint4 u; s16x8 s; } fbh, fbl;
            fbh.u = *(const uint4*)(wh + off);
            fbl.u = *(const uint4*)(wl + off);
            acc[t] = __builtin_amdgcn_mfma_f32_16x16x32_bf16(fah.s, fbh.s, acc[t], 0, 0, 0);
            acc[t] = __builtin_amdgcn_mfma_f32_16x16x32_bf16(fah.s, fbl.s, acc[t], 0, 0, 0);
            acc[t] = __builtin_amdgcn_mfma_f32_16x16x32_bf16(fal.s, fbh.s, acc[t], 0, 0, 0);
        }
    }
    // epilogue writes OUT buffer; IN readers protected by the PREVIOUS
    // layer's barrier, OUT's previous readers finished one barrier ago.
    const int orow = rs_ * 16 + (l >> 4) * 4;
#pragma unroll
    for (int t = 0; t < NT; t++) {
        int colg = (cq * NT + t) * 16 + (l & 15);
        float bv = bias[colg];
#pragma unroll
        for (int i = 0; i < 4; i++) {
            int row = orow + i;
            float sc = L0S ? ldeg[row] : 1.0f;
            float o = acc[t][i] + sc * bv;
            if (RELU) o = fmaxf(o, 0.0f);
            unsigned short h = f2bh(o);
            oh[aswz(row, colg)] = h;
            ol[aswz(row, colg)] = f2bh(o - bh2f(h));
            if (state_g != nullptr && base + row < n)
                state_g[(base + row) * 64 + colg] = o;
        }
    }
    __syncthreads();   // OUT visible to next layer
}

// ===========================================================================
// MLP kernel: stage agg -> buf0, x -> buf1 cols 64..95; 6 ping-pong MFMA
// layers (one barrier each) + pW3. LDS = 4 x 16KB + ldeg ~= 64.3KB.
// launch_bounds(1024,4): empirical VGPR cap 64 (r8 mapping) -> 4 waves/SIMD.
// ===========================================================================
template<int K0>
__global__ __launch_bounds__(MTPB, 4)
void mlp_kernel(const float* __restrict__ agg, const float* __restrict__ deg,
                const float* __restrict__ xg,
                const unsigned short* w0h, const unsigned short* w0l,
                const unsigned short* u1h, const unsigned short* u1l,
                const unsigned short* u2h, const unsigned short* u2l,
                const unsigned short* u3h, const unsigned short* u3l,
                const unsigned short* p1h, const unsigned short* p1l,
                const unsigned short* p2h, const unsigned short* p2l,
                const float* __restrict__ b0, const float* __restrict__ ub1,
                const float* __restrict__ ub2, const float* __restrict__ ub3,
                const float* __restrict__ pb1, const float* __restrict__ pb2,
                const float* __restrict__ pW3, const float* __restrict__ pb3,
                float* __restrict__ state_g, float* __restrict__ outg, int n)
{
    __shared__ unsigned short a0h[64 * 128];
    __shared__ unsigned short a0l[64 * 128];
    __shared__ unsigned short a1h[64 * 128];
    __shared__ unsigned short a1l[64 * 128];
    __shared__ float ldeg[BM];

    const int tid = threadIdx.x;
    const long base = (long)blockIdx.x * BM;
    constexpr int NKS0 = (K0 == 64) ? 2 : 1;
    constexpr int K0PAD = NKS0 * 32;

    // ---- stage: buf0 cols [0,K0PAD) = agg(+zeros); buf1 cols [64,96) = x(+zeros)
    for (int idx = tid; idx < BM * K0PAD; idx += MTPB) {
        int node = idx / K0PAD, c = idx % K0PAD;
        float v = 0.0f;
        if (c < K0 && base + node < n) v = agg[(base + node) * K0 + c];
        unsigned short h = f2bh(v);
        a0h[aswz(node, c)] = h;
        a0l[aswz(node, c)] = f2bh(v - bh2f(h));
    }
    for (int idx = tid; idx < BM * 32; idx += MTPB) {
        int node = idx >> 5, j = idx & 31;
        float v = (j < 3 && base + node < n) ? xg[(base + node) * 3 + j] : 0.0f;
        unsigned short h = f2bh(v);
        a1h[aswz(node, 64 + j)] = h;
        a1l[aswz(node, 64 + j)] = f2bh(v - bh2f(h));
    }
    if (tid < BM) ldeg[tid] = (base + tid < n) ? deg[base + tid] : 0.0f;
    __syncthreads();

    // layer0: K0 -> 64 (deg-scaled bias) : buf0 -> buf1 (x already at 64..95)
    mfma_gemm<NKS0, 1, false, true >(a0h, a0l, a1h, a1l, w0h, w0l, b0, ldeg, nullptr, base, n);
    // update MLP: 96(67) -> 128 relu, 128 -> 128 relu, 128 -> 64 (state out)
    mfma_gemm<3, 2, true,  false>(a1h, a1l, a0h, a0l, u1h, u1l, ub1, ldeg, nullptr, base, n);
    mfma_gemm<4, 2, true,  false>(a0h, a0l, a1h, a1l, u2h, u2l, ub2, ldeg, nullptr, base, n);
    mfma_gemm<4, 1, false, false>(a1h, a1l, a0h, a0l, u3h, u3l, ub3, ldeg, state_g, base, n);
    // predictor: 64 -> 128 relu, 128 -> 128 relu
    mfma_gemm<2, 2, true,  false>(a0h, a0l, a1h, a1l, p1h, p1l, pb1, ldeg, nullptr, base, n);
    mfma_gemm<4, 2, true,  false>(a1h, a1l, a0h, a0l, p2h, p2l, pb2, ldeg, nullptr, base, n);

    // ---- pW3: 128 -> 2 on VALU (reconstruct fp32 act = hi + lo) from buf0
    if (tid < 128) {
        int r = tid >> 1, c = tid & 1;
        float acc = pb3[c];
        for (int k = 0; k < 128; k++) {
            float f = bh2f(a0h[aswz(r, k)]) + bh2f(a0l[aswz(r, k)]);
            acc = fmaf(f, pW3[k * 2 + c], acc);
        }
        if (base + r < n) outg[(base + r) * 2 + c] = acc;
    }
}

// ===========================================================================
extern "C" void kernel_launch(void* const* d_in, const int* in_sizes, int n_in,
                              void* d_out, int out_size, void* d_ws, size_t ws_size,
                              hipStream_t stream)
{
    const float* x    = (const float*)d_in[0];
    const int*   ei   = (const int*)d_in[1];
    // d_in[2] = gate_type: fixed ordering [VAR*nvar, NEGVAR*nvar, CLAUSE*ncla]
    const float* posr = (const float*)d_in[3];
    const float* Wr   = (const float*)d_in[4];
    const float* br   = (const float*)d_in[5];
    const float* Wc   = (const float*)d_in[6];
    const float* bc   = (const float*)d_in[7];
    const float* uW1  = (const float*)d_in[8];
    const float* ub1  = (const float*)d_in[9];
    const float* uW2  = (const float*)d_in[10];
    const float* ub2  = (const float*)d_in[11];
    const float* uW3  = (const float*)d_in[12];
    const float* ub3  = (const float*)d_in[13];
    const float* pW1  = (const float*)d_in[14];
    const float* pb1  = (const float*)d_in[15];
    const float* pW2  = (const float*)d_in[16];
    const float* pb2  = (const float*)d_in[17];
    const float* pW3  = (const float*)d_in[18];
    const float* pb3  = (const float*)d_in[19];

    const int N     = in_sizes[0] / 3;
    const int E     = in_sizes[1] / 2;
    const int nvar  = in_sizes[3] / 16;
    const int nvar2 = 2 * nvar;
    const int ncla  = N - nvar2;

    // workspace carve-out
    int* cnt    = (int*)d_ws;              // [N]
    int* rs     = cnt + N;                 // [N+1]
    int* cursor = rs + N + 1;              // [N]
    int* part   = cursor + N;              // [2048]
    int* col    = part + 2048;             // [E]
    size_t foff = ((size_t)(col + E - (int*)d_ws) + 3) & ~(size_t)3;
    float* state = (float*)d_ws + foff;    // [2nvar*64]
    float* agg_v = state + (size_t)nvar2 * 64;   // [2nvar*16]
    float* deg_v = agg_v + (size_t)nvar2 * 16;   // [2nvar]
    float* agg_c = deg_v + nvar2;                // [ncla*64]
    float* deg_c = agg_c + (size_t)ncla * 64;    // [ncla]
    uintptr_t wp = ((uintptr_t)(deg_c + ncla) + 15) & ~(uintptr_t)15;
    unsigned short* H = (unsigned short*)wp;     // fragment-ordered bf16 hi
    const int TH = 67584;                        // total ushorts of all layers
    unsigned short* L = H + TH;                  // bf16 lo
    // per-layer offsets (C*Kpad ushorts each)
    const int oW0v = 0, oW0c = 2048, oU1 = 6144, oU2 = 18432,
              oU3 = 34816, oP1 = 43008, oP2 = 51200;

    // ---- weight prep (tiny, once per call)
    prep_w<<<1, 256, 0, stream>>>(Wr, 16, 64, 1, H + oW0v, L + oW0v);
    prep_w<<<2, 256, 0, stream>>>(Wc, 64, 64, 2, H + oW0c, L + oW0c);
    prep_w<<<6, 256, 0, stream>>>(uW1, 67, 128, 3, H + oU1, L + oU1);
    prep_w<<<8, 256, 0, stream>>>(uW2, 128, 128, 4, H + oU2, L + oU2);
    prep_w<<<4, 256, 0, stream>>>(uW3, 128, 64, 4, H + oU3, L + oU3);
    prep_w<<<4, 256, 0, stream>>>(pW1, 64, 128, 2, H + oP1, L + oP1);
    prep_w<<<8, 256, 0, stream>>>(pW2, 128, 128, 4, H + oP2, L + oP2);

    hipMemsetAsync(cnt, 0, (size_t)N * sizeof(int), stream);

    const int nb = (N + 2047) / 2048;
    count_kernel<<<(E + 255) / 256, 256, 0, stream>>>(ei, cnt, E);
    scan_blocks<<<nb, 256, 0, stream>>>(cnt, rs, part, N);
    scan_part<<<1, 256, 0, stream>>>(part, nb);
    scan_fixup<<<(N + 255) / 256, 256, 0, stream>>>(rs, cursor, part, N, E);
    scatter_kernel<<<(E + 255) / 256, 256, 0, stream>>>(ei, cursor, col, E);

    {   // var/negvar gather (CSR -> agg_v, deg_v)
        int blocks = (nvar2 + 31) / 32;
        gather_var_kernel<<<blocks, 256, 0, stream>>>(rs, col, posr,
                                                      agg_v, deg_v, nvar, nvar2);
    }
    {   // var/negvar MLP (writes state + out)
        int blocks = (nvar2 + BM - 1) / BM;
        mlp_kernel<16><<<blocks, MTPB, 0, stream>>>(
            agg_v, deg_v, x,
            H + oW0v, L + oW0v, H + oU1, L + oU1, H + oU2, L + oU2,
            H + oU3, L + oU3, H + oP1, L + oP1, H + oP2, L + oP2,
            br, ub1, ub2, ub3, pb1, pb2, pW3, pb3,
            state, (float*)d_out, nvar2);
    }
    {   // clause gather (CSR rows offset by 2nvar -> agg_c, deg_c)
        int blocks = (ncla + 31) / 32;
        gather_cla_kernel<<<blocks, 256, 0, stream>>>(rs + nvar2, col, state,
                                                      agg_c, deg_c, nvar2, ncla);
    }
    {   // clause MLP
        int blocks = (ncla + BM - 1) / BM;
        mlp_kernel<64><<<blocks, MTPB, 0, stream>>>(
            agg_c, deg_c, x + (size_t)nvar2 * 3,
            H + oW0c, L + oW0c, H + oU1, L + oU1, H + oU2, L + oU2,
            H + oU3, L + oU3, H + oP1, L + oP1, H + oP2, L + oP2,
            bc, ub1, ub2, ub3, pb1, pb2, pW3, pb3,
            nullptr, (float*)d_out + (size_t)nvar2 * 2, ncla);
    }
}

// Round 16
// 997.509 us; speedup vs baseline: 1.6635x; 1.1854x over previous
//
#include <hip/hip_runtime.h>

#define MTPB 1024    // MLP kernel: 16 waves
#define BM 64
#define SCHUNK 8192  // edges per (chunk, range) block in partitioned passes

typedef float f32x4 __attribute__((ext_vector_type(4)));
typedef short s16x8 __attribute__((ext_vector_type(8)));

// ===========================================================================
// bf16 split helpers
// ===========================================================================
__device__ __forceinline__ unsigned short f2bh(float f)
{
    unsigned u = __float_as_uint(f);
    unsigned r = u + 0x7fffu + ((u >> 16) & 1u);
    return (unsigned short)(r >> 16);
}
__device__ __forceinline__ float bh2f(unsigned short h)
{
    return __uint_as_float((unsigned)h << 16);
}

// act LDS swizzle (ushort units): 16B slot index XOR'd with row&7
__device__ __forceinline__ int aswz(int r, int k)
{
    return r * 128 + ((((k >> 3) ^ (r & 7)) << 3) | (k & 7));
}

// ===========================================================================
// CSR build, XCD-range-partitioned: count -> scan -> fixup -> scatter.
// count/scatter process edges in 8 dst-range passes; range = blockIdx&7 so
// all blocks of one range land on one XCD (round-robin dispatch) and that
// range's cnt/cursor/col windows stay dense in its private L2. r15's flat
// scatter wrote 257MB HBM (64B line per 4B store); windows ~2MB fix that.
// ===========================================================================
__global__ void count_kernel(const int* __restrict__ ei, int* __restrict__ cnt,
                             int E, int N8)
{
    int r = blockIdx.x & 7;
    int chunk = blockIdx.x >> 3;
    int lo = r * N8, hi = lo + N8;
    int e0 = chunk * SCHUNK;
    int e1 = e0 + SCHUNK; if (e1 > E) e1 = E;
    for (int e = e0 + threadIdx.x; e < e1; e += blockDim.x) {
        int d = ei[E + e];
        if (d >= lo && d < hi) atomicAdd(cnt + d, 1);
    }
}

__global__ void scan_blocks(const int* __restrict__ cnt, int* __restrict__ rs,
                            int* __restrict__ part, int N)
{
    __shared__ int sums[256];
    int t = threadIdx.x;
    int base = blockIdx.x * 2048 + t * 8;
    int v[8], s = 0;
#pragma unroll
    for (int i = 0; i < 8; i++) { int idx = base + i; v[i] = (idx < N) ? cnt[idx] : 0; s += v[i]; }
    sums[t] = s;
    __syncthreads();
    for (int off = 1; off < 256; off <<= 1) {
        int x = (t >= off) ? sums[t - off] : 0;
        __syncthreads();
        if (t >= off) sums[t] += x;
        __syncthreads();
    }
    int run = (t == 0) ? 0 : sums[t - 1];
#pragma unroll
    for (int i = 0; i < 8; i++) { int idx = base + i; if (idx < N) rs[idx] = run; run += v[i]; }
    if (t == 255) part[blockIdx.x] = sums[255];
}

__global__ void scan_part(int* __restrict__ part, int nb)
{
    __shared__ int sums[256];
    int t = threadIdx.x;
    int base = t * 8;
    int v[8], s = 0;
#pragma unroll
    for (int i = 0; i < 8; i++) { int idx = base + i; v[i] = (idx < nb) ? part[idx] : 0; s += v[i]; }
    sums[t] = s;
    __syncthreads();
    for (int off = 1; off < 256; off <<= 1) {
        int x = (t >= off) ? sums[t - off] : 0;
        __syncthreads();
        if (t >= off) sums[t] += x;
        __syncthreads();
    }
    int run = (t == 0) ? 0 : sums[t - 1];
#pragma unroll
    for (int i = 0; i < 8; i++) { int idx = base + i; if (idx < nb) part[idx] = run; run += v[i]; }
}

__global__ void scan_fixup(int* __restrict__ rs, int* __restrict__ cursor,
                           const int* __restrict__ part, int N, int E)
{
    int i = blockIdx.x * blockDim.x + threadIdx.x;
    if (i < N) { int v = rs[i] + part[i >> 11]; rs[i] = v; cursor[i] = v; }
    if (i == 0) rs[N] = E;
}

__global__ void scatter_kernel(const int* __restrict__ ei, int* __restrict__ cursor,
                               int* __restrict__ col, int E, int N8)
{
    int r = blockIdx.x & 7;
    int chunk = blockIdx.x >> 3;
    int lo = r * N8, hi = lo + N8;
    int e0 = chunk * SCHUNK;
    int e1 = e0 + SCHUNK; if (e1 > E) e1 = E;
    for (int e = e0 + threadIdx.x; e < e1; e += blockDim.x) {
        int d = ei[E + e];
        if (d >= lo && d < hi) {
            int p = atomicAdd(cursor + d, 1);
            col[p] = ei[e];
        }
    }
}

// ===========================================================================
// Standalone CSR gathers (separate kernels so their register pressure never
// touches the MLP kernel — r9/r11 lesson). Latency-bound, no launch bounds.
// ===========================================================================
__global__ void gather_cla_kernel(const int* __restrict__ rs, const int* __restrict__ col,
                                  const float* __restrict__ state,
                                  float* __restrict__ agg, float* __restrict__ deg,
                                  int nvar2, int n)
{
    int gwave = (blockIdx.x * blockDim.x + threadIdx.x) >> 6;
    int lane = threadIdx.x & 63;
    for (int i = 0; i < 8; i++) {
        int node = gwave * 8 + i;
        if (node >= n) return;
        int d0 = rs[node], d1 = rs[node + 1];
        float acc = 0.0f;
        int e = d0;
        for (; e + 4 <= d1; e += 4) {
            int s0 = col[e], s1 = col[e + 1], s2 = col[e + 2], s3 = col[e + 3];
            float a0 = (s0 < nvar2) ? state[(long)s0 * 64 + lane] : 0.0f;
            float a1 = (s1 < nvar2) ? state[(long)s1 * 64 + lane] : 0.0f;
            float a2 = (s2 < nvar2) ? state[(long)s2 * 64 + lane] : 0.0f;
            float a3 = (s3 < nvar2) ? state[(long)s3 * 64 + lane] : 0.0f;
            acc += a0 + a1 + a2 + a3;
        }
        for (; e < d1; e++) {
            int s = col[e];
            if (s < nvar2) acc += state[(long)s * 64 + lane];
        }
        agg[(long)node * 64 + lane] = acc;
        if (lane == 0) deg[node] = (float)(d1 - d0);
    }
}

__global__ void gather_var_kernel(const int* __restrict__ rs, const int* __restrict__ col,
                                  const float* __restrict__ posr,
                                  float* __restrict__ agg, float* __restrict__ deg,
                                  int nvar, int n2)
{
    int gwave = (blockIdx.x * blockDim.x + threadIdx.x) >> 6;
    int lane = threadIdx.x & 63;
    int f = lane & 15, sub = lane >> 4;
    int nvar2 = 2 * nvar;
    for (int i = 0; i < 2; i++) {
        int node = gwave * 8 + i * 4 + sub;
        if (node < n2) {
            int d0 = rs[node], d1 = rs[node + 1];
            float acc = 0.0f;
            int e = d0;
            for (; e + 2 <= d1; e += 2) {
                int s0 = col[e], s1 = col[e + 1];
                float a0 = 0.0f, a1 = 0.0f;
                if (s0 < nvar2) {
                    a0 = posr[(long)((s0 < nvar) ? s0 : s0 - nvar) * 16 + f];
                    if (s0 >= nvar) a0 = -a0;
                }
                if (s1 < nvar2) {
                    a1 = posr[(long)((s1 < nvar) ? s1 : s1 - nvar) * 16 + f];
                    if (s1 >= nvar) a1 = -a1;
                }
                acc += a0 + a1;
            }
            for (; e < d1; e++) {
                int s = col[e];
                if (s < nvar2) {
                    float a = posr[(long)((s < nvar) ? s : s - nvar) * 16 + f];
                    acc += (s < nvar) ? a : -a;
                }
            }
            agg[(long)node * 16 + f] = acc;
            if (f == 0) deg[node] = (float)(d1 - d0);
        }
    }
}

// ===========================================================================
// Weight prep: fp32 W[K][C] -> fragment-ordered bf16 hi/lo for
// mfma_f32_16x16x32_bf16 B-operand. Lane l of fragment (col-tile ct, k-step
// ks): col = ct*16 + (l&15), k = ks*32 + 4*(l>>4) + (i&3) + 16*(i>>2).
// Stored so each lane's 8 bf16 are one contiguous 16B load.
// ===========================================================================
__global__ void prep_w(const float* __restrict__ W, int K_real, int C, int NKS,
                       unsigned short* __restrict__ dhi, unsigned short* __restrict__ dlo)
{
    int t = blockIdx.x * blockDim.x + threadIdx.x;
    int total = (C / 16) * NKS * 64;
    if (t >= total) return;
    int l = t & 63;
    int rest = t >> 6;
    int ks = rest % NKS;
    int ct = rest / NKS;
    int colg = ct * 16 + (l & 15);
#pragma unroll
    for (int i = 0; i < 8; i++) {
        int k = ks * 32 + 4 * (l >> 4) + (i & 3) + 16 * (i >> 2);
        float v = (k < K_real) ? W[(long)k * C + colg] : 0.0f;
        unsigned short h = f2bh(v);
        dhi[(long)t * 8 + i] = h;
        dlo[(long)t * 8 + i] = f2bh(v - bh2f(h));
    }
}

// ===========================================================================
// Split-bf16 MFMA GEMM layer, PING-PONG buffers (in != out), 16 waves:
// wave = (row-stripe w&3) x (col-quarter w>>2); NT tiles/wave (C = NT*64).
// 3 MFMA per (ks,tile): hi*hi + hi*lo + lo*hi = fp32-grade accuracy.
// ONE barrier per layer (epilogue writes a different buffer than reads).
// ===========================================================================
template<int NKS, int NT, bool RELU, bool L0S>
__device__ __forceinline__ void mfma_gemm(
    const unsigned short* __restrict__ ih, const unsigned short* __restrict__ il,
    unsigned short* __restrict__ oh, unsigned short* __restrict__ ol,
    const unsigned short* __restrict__ wh, const unsigned short* __restrict__ wl,
    const float* __restrict__ bias, const float* __restrict__ ldeg,
    float* __restrict__ state_g, long base, int n)
{
    const int tid = threadIdx.x;
    const int w = tid >> 6, l = tid & 63;
    const int rs_ = w & 3;            // row stripe (16 rows)
    const int cq = w >> 2;            // col quarter
    const int ar = rs_ * 16 + (l & 15);
    const int ag = (l >> 4) * 4;

    f32x4 acc[NT];
#pragma unroll
    for (int t = 0; t < NT; t++) { f32x4 z = {0.f, 0.f, 0.f, 0.f}; acc[t] = z; }

#pragma unroll
    for (int ks = 0; ks < NKS; ks++) {
        int k0 = ks * 32 + ag;
        uint2 h0 = *(const uint2*)(ih + aswz(ar, k0));
        uint2 h1 = *(const uint2*)(ih + aswz(ar, k0 + 16));
        uint2 g0 = *(const uint2*)(il + aswz(ar, k0));
        uint2 g1 = *(const uint2*)(il + aswz(ar, k0 + 16));
        union { uint4 u; s16x8 s; } fah, fal;
        fah.u = make_uint4(h0.x, h0.y, h1.x, h1.y);
        fal.u = make_uint4(g0.x, g0.y, g1.x, g1.y);
#pragma unroll
        for (int t = 0; t < NT; t++) {
            int ct = cq * NT + t;
            long off = (long)((ct * NKS + ks) * 64 + l) * 8;
            union { uint4 u; s16x8 s; } fbh, fbl;
            fbh.u = *(const uint4*)(wh + off);
            fbl.u = *(const uint4*)(wl + off);
            acc[t] = __builtin_amdgcn_mfma_f32_16x16x32_bf16(fah.s, fbh.s, acc[t], 0, 0, 0);
            acc[t] = __builtin_amdgcn_mfma_f32_16x16x32_bf16(fah.s, fbl.s, acc[t], 0, 0, 0);
            acc[t] = __builtin_amdgcn_mfma_f32_16x16x32_bf16(fal.s, fbh.s, acc[t], 0, 0, 0);
        }
    }
    // epilogue writes OUT buffer; IN readers protected by the PREVIOUS
    // layer's barrier, OUT's previous readers finished one barrier ago.
    const int orow = rs_ * 16 + (l >> 4) * 4;
#pragma unroll
    for (int t = 0; t < NT; t++) {
        int colg = (cq * NT + t) * 16 + (l & 15);
        float bv = bias[colg];
#pragma unroll
        for (int i = 0; i < 4; i++) {
            int row = orow + i;
            float sc = L0S ? ldeg[row] : 1.0f;
            float o = acc[t][i] + sc * bv;
            if (RELU) o = fmaxf(o, 0.0f);
            unsigned short h = f2bh(o);
            oh[aswz(row, colg)] = h;
            ol[aswz(row, colg)] = f2bh(o - bh2f(h));
            if (state_g != nullptr && base + row < n)
                state_g[(base + row) * 64 + colg] = o;
        }
    }
    __syncthreads();   // OUT visible to next layer
}

// ===========================================================================
// MLP kernel: stage agg -> buf0, x -> buf1 cols 64..95; 6 ping-pong MFMA
// layers (one barrier each) + pW3. LDS = 4 x 16KB + ldeg ~= 64.3KB.
// launch_bounds(1024,4): empirical VGPR cap 64 (r8 mapping) -> 4 waves/SIMD.
// ===========================================================================
template<int K0>
__global__ __launch_bounds__(MTPB, 4)
void mlp_kernel(const float* __restrict__ agg, const float* __restrict__ deg,
                const float* __restrict__ xg,
                const unsigned short* w0h, const unsigned short* w0l,
                const unsigned short* u1h, const unsigned short* u1l,
                const unsigned short* u2h, const unsigned short* u2l,
                const unsigned short* u3h, const unsigned short* u3l,
                const unsigned short* p1h, const unsigned short* p1l,
                const unsigned short* p2h, const unsigned short* p2l,
                const float* __restrict__ b0, const float* __restrict__ ub1,
                const float* __restrict__ ub2, const float* __restrict__ ub3,
                const float* __restrict__ pb1, const float* __restrict__ pb2,
                const float* __restrict__ pW3, const float* __restrict__ pb3,
                float* __restrict__ state_g, float* __restrict__ outg, int n)
{
    __shared__ unsigned short a0h[64 * 128];
    __shared__ unsigned short a0l[64 * 128];
    __shared__ unsigned short a1h[64 * 128];
    __shared__ unsigned short a1l[64 * 128];
    __shared__ float ldeg[BM];

    const int tid = threadIdx.x;
    const long base = (long)blockIdx.x * BM;
    constexpr int NKS0 = (K0 == 64) ? 2 : 1;
    constexpr int K0PAD = NKS0 * 32;

    // ---- stage: buf0 cols [0,K0PAD) = agg(+zeros); buf1 cols [64,96) = x(+zeros)
    for (int idx = tid; idx < BM * K0PAD; idx += MTPB) {
        int node = idx / K0PAD, c = idx % K0PAD;
        float v = 0.0f;
        if (c < K0 && base + node < n) v = agg[(base + node) * K0 + c];
        unsigned short h = f2bh(v);
        a0h[aswz(node, c)] = h;
        a0l[aswz(node, c)] = f2bh(v - bh2f(h));
    }
    for (int idx = tid; idx < BM * 32; idx += MTPB) {
        int node = idx >> 5, j = idx & 31;
        float v = (j < 3 && base + node < n) ? xg[(base + node) * 3 + j] : 0.0f;
        unsigned short h = f2bh(v);
        a1h[aswz(node, 64 + j)] = h;
        a1l[aswz(node, 64 + j)] = f2bh(v - bh2f(h));
    }
    if (tid < BM) ldeg[tid] = (base + tid < n) ? deg[base + tid] : 0.0f;
    __syncthreads();

    // layer0: K0 -> 64 (deg-scaled bias) : buf0 -> buf1 (x already at 64..95)
    mfma_gemm<NKS0, 1, false, true >(a0h, a0l, a1h, a1l, w0h, w0l, b0, ldeg, nullptr, base, n);
    // update MLP: 96(67) -> 128 relu, 128 -> 128 relu, 128 -> 64 (state out)
    mfma_gemm<3, 2, true,  false>(a1h, a1l, a0h, a0l, u1h, u1l, ub1, ldeg, nullptr, base, n);
    mfma_gemm<4, 2, true,  false>(a0h, a0l, a1h, a1l, u2h, u2l, ub2, ldeg, nullptr, base, n);
    mfma_gemm<4, 1, false, false>(a1h, a1l, a0h, a0l, u3h, u3l, ub3, ldeg, state_g, base, n);
    // predictor: 64 -> 128 relu, 128 -> 128 relu
    mfma_gemm<2, 2, true,  false>(a0h, a0l, a1h, a1l, p1h, p1l, pb1, ldeg, nullptr, base, n);
    mfma_gemm<4, 2, true,  false>(a1h, a1l, a0h, a0l, p2h, p2l, pb2, ldeg, nullptr, base, n);

    // ---- pW3: 128 -> 2 on VALU (reconstruct fp32 act = hi + lo) from buf0
    if (tid < 128) {
        int r = tid >> 1, c = tid & 1;
        float acc = pb3[c];
        for (int k = 0; k < 128; k++) {
            float f = bh2f(a0h[aswz(r, k)]) + bh2f(a0l[aswz(r, k)]);
            acc = fmaf(f, pW3[k * 2 + c], acc);
        }
        if (base + r < n) outg[(base + r) * 2 + c] = acc;
    }
}

// ===========================================================================
extern "C" void kernel_launch(void* const* d_in, const int* in_sizes, int n_in,
                              void* d_out, int out_size, void* d_ws, size_t ws_size,
                              hipStream_t stream)
{
    const float* x    = (const float*)d_in[0];
    const int*   ei   = (const int*)d_in[1];
    // d_in[2] = gate_type: fixed ordering [VAR*nvar, NEGVAR*nvar, CLAUSE*ncla]
    const float* posr = (const float*)d_in[3];
    const float* Wr   = (const float*)d_in[4];
    const float* br   = (const float*)d_in[5];
    const float* Wc   = (const float*)d_in[6];
    const float* bc   = (const float*)d_in[7];
    const float* uW1  = (const float*)d_in[8];
    const float* ub1  = (const float*)d_in[9];
    const float* uW2  = (const float*)d_in[10];
    const float* ub2  = (const float*)d_in[11];
    const float* uW3  = (const float*)d_in[12];
    const float* ub3  = (const float*)d_in[13];
    const float* pW1  = (const float*)d_in[14];
    const float* pb1  = (const float*)d_in[15];
    const float* pW2  = (const float*)d_in[16];
    const float* pb2  = (const float*)d_in[17];
    const float* pW3  = (const float*)d_in[18];
    const float* pb3  = (const float*)d_in[19];

    const int N     = in_sizes[0] / 3;
    const int E     = in_sizes[1] / 2;
    const int nvar  = in_sizes[3] / 16;
    const int nvar2 = 2 * nvar;
    const int ncla  = N - nvar2;
    const int N8    = (N + 7) / 8;

    // workspace carve-out
    int* cnt    = (int*)d_ws;              // [N]
    int* rs     = cnt + N;                 // [N+1]
    int* cursor = rs + N + 1;              // [N]
    int* part   = cursor + N;              // [2048]
    int* col    = part + 2048;             // [E]
    size_t foff = ((size_t)(col + E - (int*)d_ws) + 3) & ~(size_t)3;
    float* state = (float*)d_ws + foff;    // [2nvar*64]
    float* agg_v = state + (size_t)nvar2 * 64;   // [2nvar*16]
    float* deg_v = agg_v + (size_t)nvar2 * 16;   // [2nvar]
    float* agg_c = deg_v + nvar2;                // [ncla*64]
    float* deg_c = agg_c + (size_t)ncla * 64;    // [ncla]
    uintptr_t wp = ((uintptr_t)(deg_c + ncla) + 15) & ~(uintptr_t)15;
    unsigned short* H = (unsigned short*)wp;     // fragment-ordered bf16 hi
    const int TH = 67584;                        // total ushorts of all layers
    unsigned short* L = H + TH;                  // bf16 lo
    // per-layer offsets (C*Kpad ushorts each)
    const int oW0v = 0, oW0c = 2048, oU1 = 6144, oU2 = 18432,
              oU3 = 34816, oP1 = 43008, oP2 = 51200;

    // ---- weight prep (tiny, once per call)
    prep_w<<<1, 256, 0, stream>>>(Wr, 16, 64, 1, H + oW0v, L + oW0v);
    prep_w<<<2, 256, 0, stream>>>(Wc, 64, 64, 2, H + oW0c, L + oW0c);
    prep_w<<<6, 256, 0, stream>>>(uW1, 67, 128, 3, H + oU1, L + oU1);
    prep_w<<<8, 256, 0, stream>>>(uW2, 128, 128, 4, H + oU2, L + oU2);
    prep_w<<<4, 256, 0, stream>>>(uW3, 128, 64, 4, H + oU3, L + oU3);
    prep_w<<<4, 256, 0, stream>>>(pW1, 64, 128, 2, H + oP1, L + oP1);
    prep_w<<<8, 256, 0, stream>>>(pW2, 128, 128, 4, H + oP2, L + oP2);

    hipMemsetAsync(cnt, 0, (size_t)N * sizeof(int), stream);

    const int nb = (N + 2047) / 2048;
    const int nchunk = (E + SCHUNK - 1) / SCHUNK;
    count_kernel<<<nchunk * 8, 256, 0, stream>>>(ei, cnt, E, N8);
    scan_blocks<<<nb, 256, 0, stream>>>(cnt, rs, part, N);
    scan_part<<<1, 256, 0, stream>>>(part, nb);
    scan_fixup<<<(N + 255) / 256, 256, 0, stream>>>(rs, cursor, part, N, E);
    scatter_kernel<<<nchunk * 8, 256, 0, stream>>>(ei, cursor, col, E, N8);

    {   // var/negvar gather (CSR -> agg_v, deg_v)
        int blocks = (nvar2 + 31) / 32;
        gather_var_kernel<<<blocks, 256, 0, stream>>>(rs, col, posr,
                                                      agg_v, deg_v, nvar, nvar2);
    }
    {   // var/negvar MLP (writes state + out)
        int blocks = (nvar2 + BM - 1) / BM;
        mlp_kernel<16><<<blocks, MTPB, 0, stream>>>(
            agg_v, deg_v, x,
            H + oW0v, L + oW0v, H + oU1, L + oU1, H + oU2, L + oU2,
            H + oU3, L + oU3, H + oP1, L + oP1, H + oP2, L + oP2,
            br, ub1, ub2, ub3, pb1, pb2, pW3, pb3,
            state, (float*)d_out, nvar2);
    }
    {   // clause gather (CSR rows offset by 2nvar -> agg_c, deg_c)
        int blocks = (ncla + 31) / 32;
        gather_cla_kernel<<<blocks, 256, 0, stream>>>(rs + nvar2, col, state,
                                                      agg_c, deg_c, nvar2, ncla);
    }
    {   // clause MLP
        int blocks = (ncla + BM - 1) / BM;
        mlp_kernel<64><<<blocks, MTPB, 0, stream>>>(
            agg_c, deg_c, x + (size_t)nvar2 * 3,
            H + oW0c, L + oW0c, H + oU1, L + oU1, H + oU2, L + oU2,
            H + oU3, L + oU3, H + oP1, L + oP1, H + oP2, L + oP2,
            bc, ub1, ub2, ub3, pb1, pb2, pW3, pb3,
            nullptr, (float*)d_out + (size_t)nvar2 * 2, ncla);
    }
}

// Round 17
// 925.398 us; speedup vs baseline: 1.7931x; 1.0779x over previous
//
#include <hip/hip_runtime.h>

#define MTPB 1024    // MLP kernel: 16 waves
#define BM 64
#define SCHUNK 8192  // edges per (chunk, range) block in partitioned passes

typedef float f32x4 __attribute__((ext_vector_type(4)));
typedef short s16x8 __attribute__((ext_vector_type(8)));

// ===========================================================================
// bf16 split helpers
// ===========================================================================
__device__ __forceinline__ unsigned short f2bh(float f)
{
    unsigned u = __float_as_uint(f);
    unsigned r = u + 0x7fffu + ((u >> 16) & 1u);
    return (unsigned short)(r >> 16);
}
__device__ __forceinline__ float bh2f(unsigned short h)
{
    return __uint_as_float((unsigned)h << 16);
}

// act LDS swizzle (ushort units): 16B slot index XOR'd with row&7
__device__ __forceinline__ int aswz(int r, int k)
{
    return r * 128 + ((((k >> 3) ^ (r & 7)) << 3) | (k & 7));
}

// ===========================================================================
// CSR build, XCD-range-partitioned: count -> scan -> fixup -> scatter.
// range = blockIdx&7 so each dst-range's cnt/cursor/col windows stay dense
// in one XCD's private L2 (r16: scatter 390 -> off the profile).
// ===========================================================================
__global__ void count_kernel(const int* __restrict__ ei, int* __restrict__ cnt,
                             int E, int N8)
{
    int r = blockIdx.x & 7;
    int chunk = blockIdx.x >> 3;
    int lo = r * N8, hi = lo + N8;
    int e0 = chunk * SCHUNK;
    int e1 = e0 + SCHUNK; if (e1 > E) e1 = E;
    for (int e = e0 + threadIdx.x; e < e1; e += blockDim.x) {
        int d = ei[E + e];
        if (d >= lo && d < hi) atomicAdd(cnt + d, 1);
    }
}

__global__ void scan_blocks(const int* __restrict__ cnt, int* __restrict__ rs,
                            int* __restrict__ part, int N)
{
    __shared__ int sums[256];
    int t = threadIdx.x;
    int base = blockIdx.x * 2048 + t * 8;
    int v[8], s = 0;
#pragma unroll
    for (int i = 0; i < 8; i++) { int idx = base + i; v[i] = (idx < N) ? cnt[idx] : 0; s += v[i]; }
    sums[t] = s;
    __syncthreads();
    for (int off = 1; off < 256; off <<= 1) {
        int x = (t >= off) ? sums[t - off] : 0;
        __syncthreads();
        if (t >= off) sums[t] += x;
        __syncthreads();
    }
    int run = (t == 0) ? 0 : sums[t - 1];
#pragma unroll
    for (int i = 0; i < 8; i++) { int idx = base + i; if (idx < N) rs[idx] = run; run += v[i]; }
    if (t == 255) part[blockIdx.x] = sums[255];
}

__global__ void scan_part(int* __restrict__ part, int nb)
{
    __shared__ int sums[256];
    int t = threadIdx.x;
    int base = t * 8;
    int v[8], s = 0;
#pragma unroll
    for (int i = 0; i < 8; i++) { int idx = base + i; v[i] = (idx < nb) ? part[idx] : 0; s += v[i]; }
    sums[t] = s;
    __syncthreads();
    for (int off = 1; off < 256; off <<= 1) {
        int x = (t >= off) ? sums[t - off] : 0;
        __syncthreads();
        if (t >= off) sums[t] += x;
        __syncthreads();
    }
    int run = (t == 0) ? 0 : sums[t - 1];
#pragma unroll
    for (int i = 0; i < 8; i++) { int idx = base + i; if (idx < nb) part[idx] = run; run += v[i]; }
}

__global__ void scan_fixup(int* __restrict__ rs, int* __restrict__ cursor,
                           const int* __restrict__ part, int N, int E)
{
    int i = blockIdx.x * blockDim.x + threadIdx.x;
    if (i < N) { int v = rs[i] + part[i >> 11]; rs[i] = v; cursor[i] = v; }
    if (i == 0) rs[N] = E;
}

__global__ void scatter_kernel(const int* __restrict__ ei, int* __restrict__ cursor,
                               int* __restrict__ col, int E, int N8)
{
    int r = blockIdx.x & 7;
    int chunk = blockIdx.x >> 3;
    int lo = r * N8, hi = lo + N8;
    int e0 = chunk * SCHUNK;
    int e1 = e0 + SCHUNK; if (e1 > E) e1 = E;
    for (int e = e0 + threadIdx.x; e < e1; e += blockDim.x) {
        int d = ei[E + e];
        if (d >= lo && d < hi) {
            int p = atomicAdd(cursor + d, 1);
            col[p] = ei[e];
        }
    }
}

// ===========================================================================
// Standalone CSR gathers (separate kernels so their register pressure never
// touches the MLP kernel — r9/r11 lesson). Latency-bound, no launch bounds.
// ===========================================================================
__global__ void gather_cla_kernel(const int* __restrict__ rs, const int* __restrict__ col,
                                  const float* __restrict__ state,
                                  float* __restrict__ agg, float* __restrict__ deg,
                                  int nvar2, int n)
{
    int gwave = (blockIdx.x * blockDim.x + threadIdx.x) >> 6;
    int lane = threadIdx.x & 63;
    for (int i = 0; i < 8; i++) {
        int node = gwave * 8 + i;
        if (node >= n) return;
        int d0 = rs[node], d1 = rs[node + 1];
        float acc = 0.0f;
        int e = d0;
        for (; e + 4 <= d1; e += 4) {
            int s0 = col[e], s1 = col[e + 1], s2 = col[e + 2], s3 = col[e + 3];
            float a0 = (s0 < nvar2) ? state[(long)s0 * 64 + lane] : 0.0f;
            float a1 = (s1 < nvar2) ? state[(long)s1 * 64 + lane] : 0.0f;
            float a2 = (s2 < nvar2) ? state[(long)s2 * 64 + lane] : 0.0f;
            float a3 = (s3 < nvar2) ? state[(long)s3 * 64 + lane] : 0.0f;
            acc += a0 + a1 + a2 + a3;
        }
        for (; e < d1; e++) {
            int s = col[e];
            if (s < nvar2) acc += state[(long)s * 64 + lane];
        }
        agg[(long)node * 64 + lane] = acc;
        if (lane == 0) deg[node] = (float)(d1 - d0);
    }
}

__global__ void gather_var_kernel(const int* __restrict__ rs, const int* __restrict__ col,
                                  const float* __restrict__ posr,
                                  float* __restrict__ agg, float* __restrict__ deg,
                                  int nvar, int n2)
{
    int gwave = (blockIdx.x * blockDim.x + threadIdx.x) >> 6;
    int lane = threadIdx.x & 63;
    int f = lane & 15, sub = lane >> 4;
    int nvar2 = 2 * nvar;
    for (int i = 0; i < 2; i++) {
        int node = gwave * 8 + i * 4 + sub;
        if (node < n2) {
            int d0 = rs[node], d1 = rs[node + 1];
            float acc = 0.0f;
            int e = d0;
            for (; e + 2 <= d1; e += 2) {
                int s0 = col[e], s1 = col[e + 1];
                float a0 = 0.0f, a1 = 0.0f;
                if (s0 < nvar2) {
                    a0 = posr[(long)((s0 < nvar) ? s0 : s0 - nvar) * 16 + f];
                    if (s0 >= nvar) a0 = -a0;
                }
                if (s1 < nvar2) {
                    a1 = posr[(long)((s1 < nvar) ? s1 : s1 - nvar) * 16 + f];
                    if (s1 >= nvar) a1 = -a1;
                }
                acc += a0 + a1;
            }
            for (; e < d1; e++) {
                int s = col[e];
                if (s < nvar2) {
                    float a = posr[(long)((s < nvar) ? s : s - nvar) * 16 + f];
                    acc += (s < nvar) ? a : -a;
                }
            }
            agg[(long)node * 16 + f] = acc;
            if (f == 0) deg[node] = (float)(d1 - d0);
        }
    }
}

// ===========================================================================
// Weight prep: fp32 W[K][C] -> fragment-ordered bf16 hi/lo for
// mfma_f32_16x16x32_bf16 B-operand. Lane l of fragment (col-tile ct, k-step
// ks): col = ct*16 + (l&15), k = ks*32 + 4*(l>>4) + (i&3) + 16*(i>>2).
// Stored so each lane's 8 bf16 are one contiguous 16B load.
// ===========================================================================
__global__ void prep_w(const float* __restrict__ W, int K_real, int C, int NKS,
                       unsigned short* __restrict__ dhi, unsigned short* __restrict__ dlo)
{
    int t = blockIdx.x * blockDim.x + threadIdx.x;
    int total = (C / 16) * NKS * 64;
    if (t >= total) return;
    int l = t & 63;
    int rest = t >> 6;
    int ks = rest % NKS;
    int ct = rest / NKS;
    int colg = ct * 16 + (l & 15);
#pragma unroll
    for (int i = 0; i < 8; i++) {
        int k = ks * 32 + 4 * (l >> 4) + (i & 3) + 16 * (i >> 2);
        float v = (k < K_real) ? W[(long)k * C + colg] : 0.0f;
        unsigned short h = f2bh(v);
        dhi[(long)t * 8 + i] = h;
        dlo[(long)t * 8 + i] = f2bh(v - bh2f(h));
    }
}

// ===========================================================================
// Split-bf16 MFMA GEMM layer, PING-PONG buffers, TILE-SEQUENTIAL:
// the col-tile loop is OUTER and unroll-1, so only ONE tile's state is live
// (acc 4 + A-frags 8 + B-frags 8 ~= 30 VGPR vs r16's 48 with NT tiles live).
// ks-loop also unroll-1 to stop the compiler batching weight loads into
// registers (r13's spill mechanism). Each tile's epilogue writes OUT
// immediately — legal because OUT != IN (ping-pong) and OUT's previous
// readers finished at the last barrier. ONE barrier per layer.
// 3 MFMA per (ks,tile): hi*hi + hi*lo + lo*hi = fp32-grade accuracy.
// ===========================================================================
template<int NKS, int NT, bool RELU, bool L0S>
__device__ __forceinline__ void mfma_gemm(
    const unsigned short* __restrict__ ih, const unsigned short* __restrict__ il,
    unsigned short* __restrict__ oh, unsigned short* __restrict__ ol,
    const unsigned short* __restrict__ wh, const unsigned short* __restrict__ wl,
    const float* __restrict__ bias, const float* __restrict__ ldeg,
    float* __restrict__ state_g, long base, int n)
{
    const int tid = threadIdx.x;
    const int w = tid >> 6, l = tid & 63;
    const int rs_ = w & 3;            // row stripe (16 rows)
    const int cq = w >> 2;            // col quarter
    const int ar = rs_ * 16 + (l & 15);
    const int ag = (l >> 4) * 4;
    const int orow = rs_ * 16 + (l >> 4) * 4;

#pragma unroll 1
    for (int t = 0; t < NT; ++t) {
        f32x4 acc = {0.f, 0.f, 0.f, 0.f};
        const int ct = cq * NT + t;
#pragma unroll 1
        for (int ks = 0; ks < NKS; ++ks) {
            int k0 = ks * 32 + ag;
            uint2 h0 = *(const uint2*)(ih + aswz(ar, k0));
            uint2 h1 = *(const uint2*)(ih + aswz(ar, k0 + 16));
            uint2 g0 = *(const uint2*)(il + aswz(ar, k0));
            uint2 g1 = *(const uint2*)(il + aswz(ar, k0 + 16));
            union { uint4 u; s16x8 s; } fah, fal, fbh, fbl;
            fah.u = make_uint4(h0.x, h0.y, h1.x, h1.y);
            fal.u = make_uint4(g0.x, g0.y, g1.x, g1.y);
            long off = (long)((ct * NKS + ks) * 64 + l) * 8;
            fbh.u = *(const uint4*)(wh + off);
            fbl.u = *(const uint4*)(wl + off);
            acc = __builtin_amdgcn_mfma_f32_16x16x32_bf16(fah.s, fbh.s, acc, 0, 0, 0);
            acc = __builtin_amdgcn_mfma_f32_16x16x32_bf16(fah.s, fbl.s, acc, 0, 0, 0);
            acc = __builtin_amdgcn_mfma_f32_16x16x32_bf16(fal.s, fbh.s, acc, 0, 0, 0);
        }
        // immediate per-tile epilogue (OUT != IN -> no barrier needed here)
        int colg = ct * 16 + (l & 15);
        float bv = bias[colg];
#pragma unroll
        for (int i = 0; i < 4; i++) {
            int row = orow + i;
            float sc = L0S ? ldeg[row] : 1.0f;
            float o = acc[i] + sc * bv;
            if (RELU) o = fmaxf(o, 0.0f);
            unsigned short h = f2bh(o);
            oh[aswz(row, colg)] = h;
            ol[aswz(row, colg)] = f2bh(o - bh2f(h));
            if (state_g != nullptr && base + row < n)
                state_g[(base + row) * 64 + colg] = o;
        }
    }
    __syncthreads();   // OUT visible to next layer
}

// ===========================================================================
// MLP kernel: stage agg -> buf0, x -> buf1 cols 64..95; 6 ping-pong MFMA
// layers (one barrier each) + pW3. LDS = 4 x 16KB + ldeg ~= 64.3KB.
// launch_bounds(1024,8): empirical VGPR cap 32 (r11 mapping); the
// tile-sequential gemm's true need ~30 fits -> 8 waves/SIMD.
// ===========================================================================
template<int K0>
__global__ __launch_bounds__(MTPB, 8)
void mlp_kernel(const float* __restrict__ agg, const float* __restrict__ deg,
                const float* __restrict__ xg,
                const unsigned short* w0h, const unsigned short* w0l,
                const unsigned short* u1h, const unsigned short* u1l,
                const unsigned short* u2h, const unsigned short* u2l,
                const unsigned short* u3h, const unsigned short* u3l,
                const unsigned short* p1h, const unsigned short* p1l,
                const unsigned short* p2h, const unsigned short* p2l,
                const float* __restrict__ b0, const float* __restrict__ ub1,
                const float* __restrict__ ub2, const float* __restrict__ ub3,
                const float* __restrict__ pb1, const float* __restrict__ pb2,
                const float* __restrict__ pW3, const float* __restrict__ pb3,
                float* __restrict__ state_g, float* __restrict__ outg, int n)
{
    __shared__ unsigned short a0h[64 * 128];
    __shared__ unsigned short a0l[64 * 128];
    __shared__ unsigned short a1h[64 * 128];
    __shared__ unsigned short a1l[64 * 128];
    __shared__ float ldeg[BM];

    const int tid = threadIdx.x;
    const long base = (long)blockIdx.x * BM;
    constexpr int NKS0 = (K0 == 64) ? 2 : 1;
    constexpr int K0PAD = NKS0 * 32;

    // ---- stage: buf0 cols [0,K0PAD) = agg(+zeros); buf1 cols [64,96) = x(+zeros)
    for (int idx = tid; idx < BM * K0PAD; idx += MTPB) {
        int node = idx / K0PAD, c = idx % K0PAD;
        float v = 0.0f;
        if (c < K0 && base + node < n) v = agg[(base + node) * K0 + c];
        unsigned short h = f2bh(v);
        a0h[aswz(node, c)] = h;
        a0l[aswz(node, c)] = f2bh(v - bh2f(h));
    }
    for (int idx = tid; idx < BM * 32; idx += MTPB) {
        int node = idx >> 5, j = idx & 31;
        float v = (j < 3 && base + node < n) ? xg[(base + node) * 3 + j] : 0.0f;
        unsigned short h = f2bh(v);
        a1h[aswz(node, 64 + j)] = h;
        a1l[aswz(node, 64 + j)] = f2bh(v - bh2f(h));
    }
    if (tid < BM) ldeg[tid] = (base + tid < n) ? deg[base + tid] : 0.0f;
    __syncthreads();

    // layer0: K0 -> 64 (deg-scaled bias) : buf0 -> buf1 (x already at 64..95)
    mfma_gemm<NKS0, 1, false, true >(a0h, a0l, a1h, a1l, w0h, w0l, b0, ldeg, nullptr, base, n);
    // update MLP: 96(67) -> 128 relu, 128 -> 128 relu, 128 -> 64 (state out)
    mfma_gemm<3, 2, true,  false>(a1h, a1l, a0h, a0l, u1h, u1l, ub1, ldeg, nullptr, base, n);
    mfma_gemm<4, 2, true,  false>(a0h, a0l, a1h, a1l, u2h, u2l, ub2, ldeg, nullptr, base, n);
    mfma_gemm<4, 1, false, false>(a1h, a1l, a0h, a0l, u3h, u3l, ub3, ldeg, state_g, base, n);
    // predictor: 64 -> 128 relu, 128 -> 128 relu
    mfma_gemm<2, 2, true,  false>(a0h, a0l, a1h, a1l, p1h, p1l, pb1, ldeg, nullptr, base, n);
    mfma_gemm<4, 2, true,  false>(a1h, a1l, a0h, a0l, p2h, p2l, pb2, ldeg, nullptr, base, n);

    // ---- pW3: 128 -> 2 on VALU (reconstruct fp32 act = hi + lo) from buf0
    if (tid < 128) {
        int r = tid >> 1, c = tid & 1;
        float acc = pb3[c];
        for (int k = 0; k < 128; k++) {
            float f = bh2f(a0h[aswz(r, k)]) + bh2f(a0l[aswz(r, k)]);
            acc = fmaf(f, pW3[k * 2 + c], acc);
        }
        if (base + r < n) outg[(base + r) * 2 + c] = acc;
    }
}

// ===========================================================================
extern "C" void kernel_launch(void* const* d_in, const int* in_sizes, int n_in,
                              void* d_out, int out_size, void* d_ws, size_t ws_size,
                              hipStream_t stream)
{
    const float* x    = (const float*)d_in[0];
    const int*   ei   = (const int*)d_in[1];
    // d_in[2] = gate_type: fixed ordering [VAR*nvar, NEGVAR*nvar, CLAUSE*ncla]
    const float* posr = (const float*)d_in[3];
    const float* Wr   = (const float*)d_in[4];
    const float* br   = (const float*)d_in[5];
    const float* Wc   = (const float*)d_in[6];
    const float* bc   = (const float*)d_in[7];
    const float* uW1  = (const float*)d_in[8];
    const float* ub1  = (const float*)d_in[9];
    const float* uW2  = (const float*)d_in[10];
    const float* ub2  = (const float*)d_in[11];
    const float* uW3  = (const float*)d_in[12];
    const float* ub3  = (const float*)d_in[13];
    const float* pW1  = (const float*)d_in[14];
    const float* pb1  = (const float*)d_in[15];
    const float* pW2  = (const float*)d_in[16];
    const float* pb2  = (const float*)d_in[17];
    const float* pW3  = (const float*)d_in[18];
    const float* pb3  = (const float*)d_in[19];

    const int N     = in_sizes[0] / 3;
    const int E     = in_sizes[1] / 2;
    const int nvar  = in_sizes[3] / 16;
    const int nvar2 = 2 * nvar;
    const int ncla  = N - nvar2;
    const int N8    = (N + 7) / 8;

    // workspace carve-out
    int* cnt    = (int*)d_ws;              // [N]
    int* rs     = cnt + N;                 // [N+1]
    int* cursor = rs + N + 1;              // [N]
    int* part   = cursor + N;              // [2048]
    int* col    = part + 2048;             // [E]
    size_t foff = ((size_t)(col + E - (int*)d_ws) + 3) & ~(size_t)3;
    float* state = (float*)d_ws + foff;    // [2nvar*64]
    float* agg_v = state + (size_t)nvar2 * 64;   // [2nvar*16]
    float* deg_v = agg_v + (size_t)nvar2 * 16;   // [2nvar]
    float* agg_c = deg_v + nvar2;                // [ncla*64]
    float* deg_c = agg_c + (size_t)ncla * 64;    // [ncla]
    uintptr_t wp = ((uintptr_t)(deg_c + ncla) + 15) & ~(uintptr_t)15;
    unsigned short* H = (unsigned short*)wp;     // fragment-ordered bf16 hi
    const int TH = 67584;                        // total ushorts of all layers
    unsigned short* L = H + TH;                  // bf16 lo
    // per-layer offsets (C*Kpad ushorts each)
    const int oW0v = 0, oW0c = 2048, oU1 = 6144, oU2 = 18432,
              oU3 = 34816, oP1 = 43008, oP2 = 51200;

    // ---- weight prep (tiny, once per call)
    prep_w<<<1, 256, 0, stream>>>(Wr, 16, 64, 1, H + oW0v, L + oW0v);
    prep_w<<<2, 256, 0, stream>>>(Wc, 64, 64, 2, H + oW0c, L + oW0c);
    prep_w<<<6, 256, 0, stream>>>(uW1, 67, 128, 3, H + oU1, L + oU1);
    prep_w<<<8, 256, 0, stream>>>(uW2, 128, 128, 4, H + oU2, L + oU2);
    prep_w<<<4, 256, 0, stream>>>(uW3, 128, 64, 4, H + oU3, L + oU3);
    prep_w<<<4, 256, 0, stream>>>(pW1, 64, 128, 2, H + oP1, L + oP1);
    prep_w<<<8, 256, 0, stream>>>(pW2, 128, 128, 4, H + oP2, L + oP2);

    hipMemsetAsync(cnt, 0, (size_t)N * sizeof(int), stream);

    const int nb = (N + 2047) / 2048;
    const int nchunk = (E + SCHUNK - 1) / SCHUNK;
    count_kernel<<<nchunk * 8, 256, 0, stream>>>(ei, cnt, E, N8);
    scan_blocks<<<nb, 256, 0, stream>>>(cnt, rs, part, N);
    scan_part<<<1, 256, 0, stream>>>(part, nb);
    scan_fixup<<<(N + 255) / 256, 256, 0, stream>>>(rs, cursor, part, N, E);
    scatter_kernel<<<nchunk * 8, 256, 0, stream>>>(ei, cursor, col, E, N8);

    {   // var/negvar gather (CSR -> agg_v, deg_v)
        int blocks = (nvar2 + 31) / 32;
        gather_var_kernel<<<blocks, 256, 0, stream>>>(rs, col, posr,
                                                      agg_v, deg_v, nvar, nvar2);
    }
    {   // var/negvar MLP (writes state + out)
        int blocks = (nvar2 + BM - 1) / BM;
        mlp_kernel<16><<<blocks, MTPB, 0, stream>>>(
            agg_v, deg_v, x,
            H + oW0v, L + oW0v, H + oU1, L + oU1, H + oU2, L + oU2,
            H + oU3, L + oU3, H + oP1, L + oP1, H + oP2, L + oP2,
            br, ub1, ub2, ub3, pb1, pb2, pW3, pb3,
            state, (float*)d_out, nvar2);
    }
    {   // clause gather (CSR rows offset by 2nvar -> agg_c, deg_c)
        int blocks = (ncla + 31) / 32;
        gather_cla_kernel<<<blocks, 256, 0, stream>>>(rs + nvar2, col, state,
                                                      agg_c, deg_c, nvar2, ncla);
    }
    {   // clause MLP
        int blocks = (ncla + BM - 1) / BM;
        mlp_kernel<64><<<blocks, MTPB, 0, stream>>>(
            agg_c, deg_c, x + (size_t)nvar2 * 3,
            H + oW0c, L + oW0c, H + oU1, L + oU1, H + oU2, L + oU2,
            H + oU3, L + oU3, H + oP1, L + oP1, H + oP2, L + oP2,
            bc, ub1, ub2, ub3, pb1, pb2, pW3, pb3,
            nullptr, (float*)d_out + (size_t)nvar2 * 2, ncla);
    }
}

// Round 18
// 873.951 us; speedup vs baseline: 1.8986x; 1.0589x over previous
//
#include <hip/hip_runtime.h>

#define MTPB 1024    // MLP kernel: 16 waves
#define BM 64
#define SCHUNK 8192  // edges per (chunk, range) block in partitioned passes

typedef float f32x4 __attribute__((ext_vector_type(4)));
typedef short s16x8 __attribute__((ext_vector_type(8)));

// ===========================================================================
// bf16 helpers. prep_w uses round-to-nearest (one-time); the MLP hot path
// uses TRUNCATION split (4 VALU ops vs 12): hi=trunc(f), lo=trunc(f-hi),
// |f-hi-lo| <= 2^-16 |f| — fp32-grade vs the 1.46e-4 threshold.
// ===========================================================================
__device__ __forceinline__ unsigned short f2bh(float f)
{
    unsigned u = __float_as_uint(f);
    unsigned r = u + 0x7fffu + ((u >> 16) & 1u);
    return (unsigned short)(r >> 16);
}
__device__ __forceinline__ float bh2f(unsigned short h)
{
    return __uint_as_float((unsigned)h << 16);
}

// ---------------------------------------------------------------------------
// Fragment-ordered act LDS layout (ushort units, row stride 128):
// row r's k-chunk ks (32 elems) is stored as 4 16B slots, slot g holding the
// MFMA A-fragment of lane-group g: elements k = ks*32 + 4g + {0..3,16..19}.
// Slot index (ks*4+g) is XOR-swizzled with (r&7) -> wave b128 reads are
// bandwidth-minimal. fpos() maps (r, k) -> ushort index for scatter writes.
// ---------------------------------------------------------------------------
__device__ __forceinline__ int fpos(int r, int k)
{
    int ks = k >> 5, p = k & 31;
    int g = (p & 15) >> 2;
    int i = (p & 3) + ((p >> 4) << 2);
    int slot = (ks * 4 + g) ^ (r & 7);
    return r * 128 + slot * 8 + i;
}

// ===========================================================================
// CSR build, XCD-range-partitioned: count -> scan -> fixup -> scatter.
// range = blockIdx&7 so each dst-range's cnt/cursor/col windows stay dense
// in one XCD's private L2 (r16: scatter 390us -> off the profile).
// ===========================================================================
__global__ void count_kernel(const int* __restrict__ ei, int* __restrict__ cnt,
                             int E, int N8)
{
    int r = blockIdx.x & 7;
    int chunk = blockIdx.x >> 3;
    int lo = r * N8, hi = lo + N8;
    int e0 = chunk * SCHUNK;
    int e1 = e0 + SCHUNK; if (e1 > E) e1 = E;
    for (int e = e0 + threadIdx.x; e < e1; e += blockDim.x) {
        int d = ei[E + e];
        if (d >= lo && d < hi) atomicAdd(cnt + d, 1);
    }
}

__global__ void scan_blocks(const int* __restrict__ cnt, int* __restrict__ rs,
                            int* __restrict__ part, int N)
{
    __shared__ int sums[256];
    int t = threadIdx.x;
    int base = blockIdx.x * 2048 + t * 8;
    int v[8], s = 0;
#pragma unroll
    for (int i = 0; i < 8; i++) { int idx = base + i; v[i] = (idx < N) ? cnt[idx] : 0; s += v[i]; }
    sums[t] = s;
    __syncthreads();
    for (int off = 1; off < 256; off <<= 1) {
        int x = (t >= off) ? sums[t - off] : 0;
        __syncthreads();
        if (t >= off) sums[t] += x;
        __syncthreads();
    }
    int run = (t == 0) ? 0 : sums[t - 1];
#pragma unroll
    for (int i = 0; i < 8; i++) { int idx = base + i; if (idx < N) rs[idx] = run; run += v[i]; }
    if (t == 255) part[blockIdx.x] = sums[255];
}

__global__ void scan_part(int* __restrict__ part, int nb)
{
    __shared__ int sums[256];
    int t = threadIdx.x;
    int base = t * 8;
    int v[8], s = 0;
#pragma unroll
    for (int i = 0; i < 8; i++) { int idx = base + i; v[i] = (idx < nb) ? part[idx] : 0; s += v[i]; }
    sums[t] = s;
    __syncthreads();
    for (int off = 1; off < 256; off <<= 1) {
        int x = (t >= off) ? sums[t - off] : 0;
        __syncthreads();
        if (t >= off) sums[t] += x;
        __syncthreads();
    }
    int run = (t == 0) ? 0 : sums[t - 1];
#pragma unroll
    for (int i = 0; i < 8; i++) { int idx = base + i; if (idx < nb) part[idx] = run; run += v[i]; }
}

__global__ void scan_fixup(int* __restrict__ rs, int* __restrict__ cursor,
                           const int* __restrict__ part, int N, int E)
{
    int i = blockIdx.x * blockDim.x + threadIdx.x;
    if (i < N) { int v = rs[i] + part[i >> 11]; rs[i] = v; cursor[i] = v; }
    if (i == 0) rs[N] = E;
}

__global__ void scatter_kernel(const int* __restrict__ ei, int* __restrict__ cursor,
                               int* __restrict__ col, int E, int N8)
{
    int r = blockIdx.x & 7;
    int chunk = blockIdx.x >> 3;
    int lo = r * N8, hi = lo + N8;
    int e0 = chunk * SCHUNK;
    int e1 = e0 + SCHUNK; if (e1 > E) e1 = E;
    for (int e = e0 + threadIdx.x; e < e1; e += blockDim.x) {
        int d = ei[E + e];
        if (d >= lo && d < hi) {
            int p = atomicAdd(cursor + d, 1);
            col[p] = ei[e];
        }
    }
}

// ===========================================================================
// Standalone CSR gathers (separate kernels so their register pressure never
// touches the MLP kernel — r9/r11 lesson). Latency-bound, no launch bounds.
// ===========================================================================
__global__ void gather_cla_kernel(const int* __restrict__ rs, const int* __restrict__ col,
                                  const float* __restrict__ state,
                                  float* __restrict__ agg, float* __restrict__ deg,
                                  int nvar2, int n)
{
    int gwave = (blockIdx.x * blockDim.x + threadIdx.x) >> 6;
    int lane = threadIdx.x & 63;
    for (int i = 0; i < 8; i++) {
        int node = gwave * 8 + i;
        if (node >= n) return;
        int d0 = rs[node], d1 = rs[node + 1];
        float acc = 0.0f;
        int e = d0;
        for (; e + 4 <= d1; e += 4) {
            int s0 = col[e], s1 = col[e + 1], s2 = col[e + 2], s3 = col[e + 3];
            float a0 = (s0 < nvar2) ? state[(long)s0 * 64 + lane] : 0.0f;
            float a1 = (s1 < nvar2) ? state[(long)s1 * 64 + lane] : 0.0f;
            float a2 = (s2 < nvar2) ? state[(long)s2 * 64 + lane] : 0.0f;
            float a3 = (s3 < nvar2) ? state[(long)s3 * 64 + lane] : 0.0f;
            acc += a0 + a1 + a2 + a3;
        }
        for (; e < d1; e++) {
            int s = col[e];
            if (s < nvar2) acc += state[(long)s * 64 + lane];
        }
        agg[(long)node * 64 + lane] = acc;
        if (lane == 0) deg[node] = (float)(d1 - d0);
    }
}

__global__ void gather_var_kernel(const int* __restrict__ rs, const int* __restrict__ col,
                                  const float* __restrict__ posr,
                                  float* __restrict__ agg, float* __restrict__ deg,
                                  int nvar, int n2)
{
    int gwave = (blockIdx.x * blockDim.x + threadIdx.x) >> 6;
    int lane = threadIdx.x & 63;
    int f = lane & 15, sub = lane >> 4;
    int nvar2 = 2 * nvar;
    for (int i = 0; i < 2; i++) {
        int node = gwave * 8 + i * 4 + sub;
        if (node < n2) {
            int d0 = rs[node], d1 = rs[node + 1];
            float acc = 0.0f;
            int e = d0;
            for (; e + 2 <= d1; e += 2) {
                int s0 = col[e], s1 = col[e + 1];
                float a0 = 0.0f, a1 = 0.0f;
                if (s0 < nvar2) {
                    a0 = posr[(long)((s0 < nvar) ? s0 : s0 - nvar) * 16 + f];
                    if (s0 >= nvar) a0 = -a0;
                }
                if (s1 < nvar2) {
                    a1 = posr[(long)((s1 < nvar) ? s1 : s1 - nvar) * 16 + f];
                    if (s1 >= nvar) a1 = -a1;
                }
                acc += a0 + a1;
            }
            for (; e < d1; e++) {
                int s = col[e];
                if (s < nvar2) {
                    float a = posr[(long)((s < nvar) ? s : s - nvar) * 16 + f];
                    acc += (s < nvar) ? a : -a;
                }
            }
            agg[(long)node * 16 + f] = acc;
            if (f == 0) deg[node] = (float)(d1 - d0);
        }
    }
}

// ===========================================================================
// Weight prep: fp32 W[K][C] -> fragment-ordered bf16 hi/lo for
// mfma_f32_16x16x32_bf16 B-operand. Lane l of fragment (col-tile ct, k-step
// ks): col = ct*16 + (l&15), k = ks*32 + 4*(l>>4) + (i&3) + 16*(i>>2).
// Stored so each lane's 8 bf16 are one contiguous 16B load.
// ===========================================================================
__global__ void prep_w(const float* __restrict__ W, int K_real, int C, int NKS,
                       unsigned short* __restrict__ dhi, unsigned short* __restrict__ dlo)
{
    int t = blockIdx.x * blockDim.x + threadIdx.x;
    int total = (C / 16) * NKS * 64;
    if (t >= total) return;
    int l = t & 63;
    int rest = t >> 6;
    int ks = rest % NKS;
    int ct = rest / NKS;
    int colg = ct * 16 + (l & 15);
#pragma unroll
    for (int i = 0; i < 8; i++) {
        int k = ks * 32 + 4 * (l >> 4) + (i & 3) + 16 * (i >> 2);
        float v = (k < K_real) ? W[(long)k * C + colg] : 0.0f;
        unsigned short h = f2bh(v);
        dhi[(long)t * 8 + i] = h;
        dlo[(long)t * 8 + i] = f2bh(v - bh2f(h));
    }
}

// ===========================================================================
// Split-bf16 MFMA GEMM layer, PING-PONG buffers, TILE-SEQUENTIAL (r17's
// 32-VGPR discipline), with FRAGMENT-ORDERED act: one ds_read_b128 per
// A-fragment (vs 2x b64 + repack). 3 MFMA per (ks,tile): hi*hi+hi*lo+lo*hi.
// Truncation hi/lo split in the epilogue (4 ops vs 12). One barrier/layer.
// ===========================================================================
template<int NKS, int NT, bool RELU, bool L0S>
__device__ __forceinline__ void mfma_gemm(
    const unsigned short* __restrict__ ih, const unsigned short* __restrict__ il,
    unsigned short* __restrict__ oh, unsigned short* __restrict__ ol,
    const unsigned short* __restrict__ wh, const unsigned short* __restrict__ wl,
    const float* __restrict__ bias, const float* __restrict__ ldeg,
    float* __restrict__ state_g, long base, int n)
{
    const int tid = threadIdx.x;
    const int w = tid >> 6, l = tid & 63;
    const int rs_ = w & 3;            // row stripe (16 rows)
    const int cq = w >> 2;            // col quarter
    const int ar = rs_ * 16 + (l & 15);
    const int abase = ar * 128;       // row base (ushorts)
    const int ax = (ar & 7) << 3;     // swizzle XOR (ushort offset)
    const int g8 = (l >> 4) << 3;     // lane-group slot offset (ushorts)
    const int orow = rs_ * 16 + (l >> 4) * 4;

#pragma unroll 1
    for (int t = 0; t < NT; ++t) {
        f32x4 acc = {0.f, 0.f, 0.f, 0.f};
        const int ct = cq * NT + t;
#pragma unroll 1
        for (int ks = 0; ks < NKS; ++ks) {
            int ao = abase + ((ks * 32 + g8) ^ ax);
            union { uint4 u; s16x8 s; } fah, fal, fbh, fbl;
            fah.u = *(const uint4*)(ih + ao);
            fal.u = *(const uint4*)(il + ao);
            long off = (long)((ct * NKS + ks) * 64 + l) * 8;
            fbh.u = *(const uint4*)(wh + off);
            fbl.u = *(const uint4*)(wl + off);
            acc = __builtin_amdgcn_mfma_f32_16x16x32_bf16(fah.s, fbh.s, acc, 0, 0, 0);
            acc = __builtin_amdgcn_mfma_f32_16x16x32_bf16(fah.s, fbl.s, acc, 0, 0, 0);
            acc = __builtin_amdgcn_mfma_f32_16x16x32_bf16(fal.s, fbh.s, acc, 0, 0, 0);
        }
        // immediate per-tile epilogue (OUT != IN -> no barrier needed here)
        int colg = ct * 16 + (l & 15);
        int ks2 = colg >> 5, p = colg & 31;
        int slot8 = ((ks2 * 4 + ((p & 15) >> 2)) << 3);
        int i2 = (p & 3) + ((p >> 4) << 2);
        float bv = bias[colg];
#pragma unroll
        for (int i = 0; i < 4; i++) {
            int row = orow + i;
            float sc = L0S ? ldeg[row] : 1.0f;
            float o = acc[i] + sc * bv;
            if (RELU) o = fmaxf(o, 0.0f);
            unsigned u = __float_as_uint(o);
            float lo = o - __uint_as_float(u & 0xffff0000u);
            int idx = row * 128 + (slot8 ^ ((row & 7) << 3)) + i2;
            oh[idx] = (unsigned short)(u >> 16);
            ol[idx] = (unsigned short)(__float_as_uint(lo) >> 16);
            if (state_g != nullptr && base + row < n)
                state_g[(base + row) * 64 + colg] = o;
        }
    }
    __syncthreads();   // OUT visible to next layer
}

// ===========================================================================
// MLP kernel: stage agg -> buf0, x -> buf1 cols 64..95 (fragment order);
// 6 ping-pong MFMA layers (one barrier each) + pW3. LDS = 4x16KB + ldeg.
// launch_bounds(1024,8): empirical VGPR cap 32; tile-sequential gemm fits.
// ===========================================================================
template<int K0>
__global__ __launch_bounds__(MTPB, 8)
void mlp_kernel(const float* __restrict__ agg, const float* __restrict__ deg,
                const float* __restrict__ xg,
                const unsigned short* w0h, const unsigned short* w0l,
                const unsigned short* u1h, const unsigned short* u1l,
                const unsigned short* u2h, const unsigned short* u2l,
                const unsigned short* u3h, const unsigned short* u3l,
                const unsigned short* p1h, const unsigned short* p1l,
                const unsigned short* p2h, const unsigned short* p2l,
                const float* __restrict__ b0, const float* __restrict__ ub1,
                const float* __restrict__ ub2, const float* __restrict__ ub3,
                const float* __restrict__ pb1, const float* __restrict__ pb2,
                const float* __restrict__ pW3, const float* __restrict__ pb3,
                float* __restrict__ state_g, float* __restrict__ outg, int n)
{
    __shared__ unsigned short a0h[64 * 128];
    __shared__ unsigned short a0l[64 * 128];
    __shared__ unsigned short a1h[64 * 128];
    __shared__ unsigned short a1l[64 * 128];
    __shared__ float ldeg[BM];

    const int tid = threadIdx.x;
    const long base = (long)blockIdx.x * BM;
    constexpr int NKS0 = (K0 == 64) ? 2 : 1;
    constexpr int K0PAD = NKS0 * 32;

    // ---- stage: buf0 cols [0,K0PAD) = agg(+zeros); buf1 cols [64,96) = x(+zeros)
    for (int idx = tid; idx < BM * K0PAD; idx += MTPB) {
        int node = idx / K0PAD, c = idx % K0PAD;
        float v = 0.0f;
        if (c < K0 && base + node < n) v = agg[(base + node) * K0 + c];
        unsigned u = __float_as_uint(v);
        float lo = v - __uint_as_float(u & 0xffff0000u);
        int fp = fpos(node, c);
        a0h[fp] = (unsigned short)(u >> 16);
        a0l[fp] = (unsigned short)(__float_as_uint(lo) >> 16);
    }
    for (int idx = tid; idx < BM * 32; idx += MTPB) {
        int node = idx >> 5, j = idx & 31;
        float v = (j < 3 && base + node < n) ? xg[(base + node) * 3 + j] : 0.0f;
        unsigned u = __float_as_uint(v);
        float lo = v - __uint_as_float(u & 0xffff0000u);
        int fp = fpos(node, 64 + j);
        a1h[fp] = (unsigned short)(u >> 16);
        a1l[fp] = (unsigned short)(__float_as_uint(lo) >> 16);
    }
    if (tid < BM) ldeg[tid] = (base + tid < n) ? deg[base + tid] : 0.0f;
    __syncthreads();

    // layer0: K0 -> 64 (deg-scaled bias) : buf0 -> buf1 (x already at 64..95)
    mfma_gemm<NKS0, 1, false, true >(a0h, a0l, a1h, a1l, w0h, w0l, b0, ldeg, nullptr, base, n);
    // update MLP: 96(67) -> 128 relu, 128 -> 128 relu, 128 -> 64 (state out)
    mfma_gemm<3, 2, true,  false>(a1h, a1l, a0h, a0l, u1h, u1l, ub1, ldeg, nullptr, base, n);
    mfma_gemm<4, 2, true,  false>(a0h, a0l, a1h, a1l, u2h, u2l, ub2, ldeg, nullptr, base, n);
    mfma_gemm<4, 1, false, false>(a1h, a1l, a0h, a0l, u3h, u3l, ub3, ldeg, state_g, base, n);
    // predictor: 64 -> 128 relu, 128 -> 128 relu
    mfma_gemm<2, 2, true,  false>(a0h, a0l, a1h, a1l, p1h, p1l, pb1, ldeg, nullptr, base, n);
    mfma_gemm<4, 2, true,  false>(a1h, a1l, a0h, a0l, p2h, p2l, pb2, ldeg, nullptr, base, n);

    // ---- pW3: 128 -> 2 on VALU (reconstruct fp32 act = hi + lo) from buf0
    if (tid < 128) {
        int r = tid >> 1, c = tid & 1;
        float acc = pb3[c];
        for (int k = 0; k < 128; k++) {
            int fp = fpos(r, k);
            float f = bh2f(a0h[fp]) + bh2f(a0l[fp]);
            acc = fmaf(f, pW3[k * 2 + c], acc);
        }
        if (base + r < n) outg[(base + r) * 2 + c] = acc;
    }
}

// ===========================================================================
extern "C" void kernel_launch(void* const* d_in, const int* in_sizes, int n_in,
                              void* d_out, int out_size, void* d_ws, size_t ws_size,
                              hipStream_t stream)
{
    const float* x    = (const float*)d_in[0];
    const int*   ei   = (const int*)d_in[1];
    // d_in[2] = gate_type: fixed ordering [VAR*nvar, NEGVAR*nvar, CLAUSE*ncla]
    const float* posr = (const float*)d_in[3];
    const float* Wr   = (const float*)d_in[4];
    const float* br   = (const float*)d_in[5];
    const float* Wc   = (const float*)d_in[6];
    const float* bc   = (const float*)d_in[7];
    const float* uW1  = (const float*)d_in[8];
    const float* ub1  = (const float*)d_in[9];
    const float* uW2  = (const float*)d_in[10];
    const float* ub2  = (const float*)d_in[11];
    const float* uW3  = (const float*)d_in[12];
    const float* ub3  = (const float*)d_in[13];
    const float* pW1  = (const float*)d_in[14];
    const float* pb1  = (const float*)d_in[15];
    const float* pW2  = (const float*)d_in[16];
    const float* pb2  = (const float*)d_in[17];
    const float* pW3  = (const float*)d_in[18];
    const float* pb3  = (const float*)d_in[19];

    const int N     = in_sizes[0] / 3;
    const int E     = in_sizes[1] / 2;
    const int nvar  = in_sizes[3] / 16;
    const int nvar2 = 2 * nvar;
    const int ncla  = N - nvar2;
    const int N8    = (N + 7) / 8;

    // workspace carve-out
    int* cnt    = (int*)d_ws;              // [N]
    int* rs     = cnt + N;                 // [N+1]
    int* cursor = rs + N + 1;              // [N]
    int* part   = cursor + N;              // [2048]
    int* col    = part + 2048;             // [E]
    size_t foff = ((size_t)(col + E - (int*)d_ws) + 3) & ~(size_t)3;
    float* state = (float*)d_ws + foff;    // [2nvar*64]
    float* agg_v = state + (size_t)nvar2 * 64;   // [2nvar*16]
    float* deg_v = agg_v + (size_t)nvar2 * 16;   // [2nvar]
    float* agg_c = deg_v + nvar2;                // [ncla*64]
    float* deg_c = agg_c + (size_t)ncla * 64;    // [ncla]
    uintptr_t wp = ((uintptr_t)(deg_c + ncla) + 15) & ~(uintptr_t)15;
    unsigned short* H = (unsigned short*)wp;     // fragment-ordered bf16 hi
    const int TH = 67584;                        // total ushorts of all layers
    unsigned short* L = H + TH;                  // bf16 lo
    // per-layer offsets (C*Kpad ushorts each)
    const int oW0v = 0, oW0c = 2048, oU1 = 6144, oU2 = 18432,
              oU3 = 34816, oP1 = 43008, oP2 = 51200;

    // ---- weight prep (tiny, once per call)
    prep_w<<<1, 256, 0, stream>>>(Wr, 16, 64, 1, H + oW0v, L + oW0v);
    prep_w<<<2, 256, 0, stream>>>(Wc, 64, 64, 2, H + oW0c, L + oW0c);
    prep_w<<<6, 256, 0, stream>>>(uW1, 67, 128, 3, H + oU1, L + oU1);
    prep_w<<<8, 256, 0, stream>>>(uW2, 128, 128, 4, H + oU2, L + oU2);
    prep_w<<<4, 256, 0, stream>>>(uW3, 128, 64, 4, H + oU3, L + oU3);
    prep_w<<<4, 256, 0, stream>>>(pW1, 64, 128, 2, H + oP1, L + oP1);
    prep_w<<<8, 256, 0, stream>>>(pW2, 128, 128, 4, H + oP2, L + oP2);

    hipMemsetAsync(cnt, 0, (size_t)N * sizeof(int), stream);

    const int nb = (N + 2047) / 2048;
    const int nchunk = (E + SCHUNK - 1) / SCHUNK;
    count_kernel<<<nchunk * 8, 256, 0, stream>>>(ei, cnt, E, N8);
    scan_blocks<<<nb, 256, 0, stream>>>(cnt, rs, part, N);
    scan_part<<<1, 256, 0, stream>>>(part, nb);
    scan_fixup<<<(N + 255) / 256, 256, 0, stream>>>(rs, cursor, part, N, E);
    scatter_kernel<<<nchunk * 8, 256, 0, stream>>>(ei, cursor, col, E, N8);

    {   // var/negvar gather (CSR -> agg_v, deg_v)
        int blocks = (nvar2 + 31) / 32;
        gather_var_kernel<<<blocks, 256, 0, stream>>>(rs, col, posr,
                                                      agg_v, deg_v, nvar, nvar2);
    }
    {   // var/negvar MLP (writes state + out)
        int blocks = (nvar2 + BM - 1) / BM;
        mlp_kernel<16><<<blocks, MTPB, 0, stream>>>(
            agg_v, deg_v, x,
            H + oW0v, L + oW0v, H + oU1, L + oU1, H + oU2, L + oU2,
            H + oU3, L + oU3, H + oP1, L + oP1, H + oP2, L + oP2,
            br, ub1, ub2, ub3, pb1, pb2, pW3, pb3,
            state, (float*)d_out, nvar2);
    }
    {   // clause gather (CSR rows offset by 2nvar -> agg_c, deg_c)
        int blocks = (ncla + 31) / 32;
        gather_cla_kernel<<<blocks, 256, 0, stream>>>(rs + nvar2, col, state,
                                                      agg_c, deg_c, nvar2, ncla);
    }
    {   // clause MLP
        int blocks = (ncla + BM - 1) / BM;
        mlp_kernel<64><<<blocks, MTPB, 0, stream>>>(
            agg_c, deg_c, x + (size_t)nvar2 * 3,
            H + oW0c, L + oW0c, H + oU1, L + oU1, H + oU2, L + oU2,
            H + oU3, L + oU3, H + oP1, L + oP1, H + oP2, L + oP2,
            bc, ub1, ub2, ub3, pb1, pb2, pW3, pb3,
            nullptr, (float*)d_out + (size_t)nvar2 * 2, ncla);
    }
}